// Round 1
// baseline (2193.904 us; speedup 1.0000x reference)
//
#include <hip/hip_runtime.h>
#include <cmath>

// Problem constants (fixed by reference setup)
#define NTOK 4096            // B*S = 2*2048
#define HD   4096            // hidden dim
#define NE   8               // experts
#define CAP  1536            // int(B*S*1.5*2/8)
#define NSEL 8192            // NTOK * TOP_K

// d_out layout (float element offsets)
#define DISP_OFF  0
#define COMB_OFF  50331648UL   // NTOK*NE*CAP
#define PROBS_OFF 100663296UL  // 2*NTOK*NE*CAP
#define AUX_OFF   100696064UL  // PROBS_OFF + NTOK*NE

// ---------------- Kernel A: h = relu(x @ W1 + b1) ----------------
// fp32 vector GEMM, 128x128 block tile, 8x8 per-thread micro-tile, BK=16.
#define BM 128
#define BN 128
#define BK 16
#define TM 8
#define TN 8

__global__ __launch_bounds__(256) void gemm_relu_kernel(
    const float* __restrict__ A,   // x  [NTOK][HD]
    const float* __restrict__ B,   // W1 [HD][HD]
    const float* __restrict__ bias,// b1 [HD]
    float* __restrict__ C)         // h  [NTOK][HD]
{
    __shared__ float As[BK][BM];   // transposed stage: As[k][m]
    __shared__ float Bs[BK][BN];

    const int tid = threadIdx.x;
    const int tx = tid & 15;       // micro col group
    const int ty = tid >> 4;       // micro row group
    const int m0 = blockIdx.y * BM;
    const int n0 = blockIdx.x * BN;

    float acc[TM][TN];
#pragma unroll
    for (int i = 0; i < TM; ++i)
#pragma unroll
        for (int j = 0; j < TN; ++j) acc[i][j] = 0.f;

    for (int k0 = 0; k0 < HD; k0 += BK) {
        // Stage A tile 128x16 (float4 along k, store transposed)
#pragma unroll
        for (int it = 0; it < 2; ++it) {
            int j = tid + 256 * it;          // 0..511
            int row = j >> 2;                // 0..127
            int kq = (j & 3) << 2;           // 0,4,8,12
            float4 av = *(const float4*)(A + (size_t)(m0 + row) * HD + k0 + kq);
            As[kq + 0][row] = av.x;
            As[kq + 1][row] = av.y;
            As[kq + 2][row] = av.z;
            As[kq + 3][row] = av.w;
        }
        // Stage B tile 16x128 (fully coalesced float4)
#pragma unroll
        for (int it = 0; it < 2; ++it) {
            int j = tid + 256 * it;          // 0..511
            int r = j >> 5;                  // 0..15
            int cq = (j & 31) << 2;          // 0..124
            *(float4*)(&Bs[r][cq]) = *(const float4*)(B + (size_t)(k0 + r) * HD + n0 + cq);
        }
        __syncthreads();
#pragma unroll
        for (int k = 0; k < BK; ++k) {
            float a[TM], b[TN];
            *(float4*)(&a[0]) = *(const float4*)(&As[k][TM * ty]);
            *(float4*)(&a[4]) = *(const float4*)(&As[k][TM * ty + 4]);
            *(float4*)(&b[0]) = *(const float4*)(&Bs[k][TN * tx]);
            *(float4*)(&b[4]) = *(const float4*)(&Bs[k][TN * tx + 4]);
#pragma unroll
            for (int i = 0; i < TM; ++i)
#pragma unroll
                for (int j = 0; j < TN; ++j) acc[i][j] += a[i] * b[j];
        }
        __syncthreads();
    }
    // Epilogue: bias + ReLU, vectorized store
#pragma unroll
    for (int i = 0; i < TM; ++i) {
        int row = m0 + TM * ty + i;
#pragma unroll
        for (int j = 0; j < TN; ++j) {
            float v = acc[i][j] + bias[n0 + TN * tx + j];
            acc[i][j] = v > 0.f ? v : 0.f;
        }
        *(float4*)(C + (size_t)row * HD + n0 + TN * tx)     = *(float4*)(&acc[i][0]);
        *(float4*)(C + (size_t)row * HD + n0 + TN * tx + 4) = *(float4*)(&acc[i][4]);
    }
}

// ---------------- Kernel B: logits = h @ W2 + b2 ----------------
// One block (256 thr) per token; per-thread 8 partial sums; LDS tree reduce.
__global__ __launch_bounds__(256) void logits_kernel(
    const float* __restrict__ h,    // [NTOK][HD]
    const float* __restrict__ W2,   // [HD][NE]
    const float* __restrict__ b2,   // [NE]
    float* __restrict__ logits)     // [NTOK][NE]
{
    const int t = blockIdx.x;
    const int tid = threadIdx.x;
    const float* hrow = h + (size_t)t * HD;

    float acc[NE];
#pragma unroll
    for (int e = 0; e < NE; ++e) acc[e] = 0.f;

    for (int f = tid; f < HD; f += 256) {
        float hv = hrow[f];
        float4 w0 = *(const float4*)(W2 + (size_t)f * NE);
        float4 w1 = *(const float4*)(W2 + (size_t)f * NE + 4);
        acc[0] += hv * w0.x; acc[1] += hv * w0.y; acc[2] += hv * w0.z; acc[3] += hv * w0.w;
        acc[4] += hv * w1.x; acc[5] += hv * w1.y; acc[6] += hv * w1.z; acc[7] += hv * w1.w;
    }

    __shared__ float red[256][NE];
#pragma unroll
    for (int e = 0; e < NE; ++e) red[tid][e] = acc[e];
    __syncthreads();
    for (int s = 128; s > 0; s >>= 1) {
        if (tid < s) {
#pragma unroll
            for (int e = 0; e < NE; ++e) red[tid][e] += red[tid + s][e];
        }
        __syncthreads();
    }
    if (tid < NE) logits[(size_t)t * NE + tid] = red[0][tid] + b2[tid];
}

// ---------------- Kernel C: softmax + top2 + renorm + partial prob sums ----
__global__ __launch_bounds__(256) void softmax_top2_kernel(
    const float* __restrict__ logits,  // [NTOK][NE]
    float* __restrict__ probs_out,     // d_out + PROBS_OFF
    float* __restrict__ top2prob,      // ws [NSEL] (renormalized)
    int* __restrict__ top2idx,         // ws [NSEL]
    float* __restrict__ partial)       // ws [gridDim][NE]
{
    const int tid = threadIdx.x;
    const int t = blockIdx.x * 256 + tid;

    float l[NE];
    *(float4*)(&l[0]) = *(const float4*)(logits + (size_t)t * NE);
    *(float4*)(&l[4]) = *(const float4*)(logits + (size_t)t * NE + 4);

    float mx = l[0];
#pragma unroll
    for (int e = 1; e < NE; ++e) mx = fmaxf(mx, l[e]);
    float p[NE], sum = 0.f;
#pragma unroll
    for (int e = 0; e < NE; ++e) { p[e] = __expf(l[e] - mx); sum += p[e]; }
    float inv = 1.f / sum;
#pragma unroll
    for (int e = 0; e < NE; ++e) p[e] *= inv;

    // write full softmax probs (final output region)
#pragma unroll
    for (int e = 0; e < NE; ++e) probs_out[(size_t)t * NE + e] = p[e];

    // top-2 on logits (monotone w/ probs); ties keep lower index (lax.top_k)
    float b1v = -1e30f, b2v = -1e30f;
    int i1 = 0, i2 = 0;
#pragma unroll
    for (int e = 0; e < NE; ++e) {
        float v = l[e];
        if (v > b1v) { b2v = b1v; i2 = i1; b1v = v; i1 = e; }
        else if (v > b2v) { b2v = v; i2 = e; }
    }
    float p1 = 0.f, p2 = 0.f;
#pragma unroll
    for (int e = 0; e < NE; ++e) { if (e == i1) p1 = p[e]; if (e == i2) p2 = p[e]; }
    float s = p1 + p2 + 1e-8f;
    top2prob[2 * t]     = p1 / s;
    top2prob[2 * t + 1] = p2 / s;
    top2idx[2 * t]      = i1;
    top2idx[2 * t + 1]  = i2;

    // per-block partial sums of full probs (for aux loss)
    __shared__ float red[256][NE];
#pragma unroll
    for (int e = 0; e < NE; ++e) red[tid][e] = p[e];
    __syncthreads();
    for (int sdx = 128; sdx > 0; sdx >>= 1) {
        if (tid < sdx) {
#pragma unroll
            for (int e = 0; e < NE; ++e) red[tid][e] += red[tid + sdx][e];
        }
        __syncthreads();
    }
    if (tid < NE) partial[blockIdx.x * NE + tid] = red[0][tid];
}

// ---------------- Kernel D: sequential-order capacity scan + slot map + aux -
// Single block, 256 threads; exact per-expert exclusive prefix over flat
// (b,s,k) order, matching the reference cumsum semantics.
__global__ __launch_bounds__(256) void scan_dispatch_kernel(
    const int* __restrict__ top2idx,   // [NSEL]
    const float* __restrict__ top2prob,// [NSEL]
    const float* __restrict__ partial, // [16][NE]
    int* __restrict__ slot_pos,        // ws [NTOK*NE], -1 = empty
    float* __restrict__ slot_val,      // ws [NTOK*NE]
    float* __restrict__ aux_out)       // d_out + AUX_OFF
{
    const int tid = threadIdx.x;
    const int ITEMS = NSEL / 256;      // 32 consecutive items per thread

    // init slot map
    for (int i = tid; i < NTOK * NE; i += 256) { slot_pos[i] = -1; slot_val[i] = 0.f; }

    // local per-expert counts
    int cnt[NE];
#pragma unroll
    for (int e = 0; e < NE; ++e) cnt[e] = 0;
    const int base = tid * ITEMS;
    for (int j = 0; j < ITEMS; ++j) {
        int v = top2idx[base + j];
#pragma unroll
        for (int e = 0; e < NE; ++e) cnt[e] += (v == e);
    }

    __shared__ int scnt[256][NE];
    __shared__ int tot[NE];
#pragma unroll
    for (int e = 0; e < NE; ++e) scnt[tid][e] = cnt[e];
    __syncthreads();

    // serial exclusive scan per expert (8 threads, 256 steps each)
    if (tid < NE) {
        int run = 0;
        for (int i = 0; i < 256; ++i) {
            int c = scnt[i][tid];
            scnt[i][tid] = run;
            run += c;
        }
        tot[tid] = run;
    }
    __syncthreads();

    int off[NE];
#pragma unroll
    for (int e = 0; e < NE; ++e) off[e] = scnt[tid][e];
    for (int j = 0; j < ITEMS; ++j) {
        int item = base + j;
        int v = top2idx[item];
        int pos = 0;
#pragma unroll
        for (int e = 0; e < NE; ++e) { if (v == e) { pos = off[e]; off[e]++; } }
        if (pos < CAP) {
            int tok = item >> 1;
            slot_pos[tok * NE + v] = pos;
            slot_val[tok * NE + v] = top2prob[item];
        }
    }

    if (tid == 0) {
        float aux = 0.f;
#pragma unroll
        for (int e = 0; e < NE; ++e) {
            float pp = 0.f;
            for (int b = 0; b < 16; ++b) pp += partial[b * NE + e];
            aux += (pp / (float)NTOK) * ((float)tot[e] / (float)NSEL);
        }
        aux_out[0] = aux * (float)NE;
    }
}

// ---------------- Kernel E: fused zero-fill + scatter of dispatch/combine ---
// Streams 2*NTOK*NE*CAP floats; per float4 decides 0 or slot value from the
// 32K-entry slot map (L1/L2 resident).
__global__ __launch_bounds__(256) void fill_outputs_kernel(
    const int* __restrict__ slot_pos,
    const float* __restrict__ slot_val,
    float* __restrict__ out)
{
    const int TOTALQ = 25165824;   // 2*NTOK*NE*CAP / 4
    const int HALFQ  = 12582912;   // dispatch region float4 count
    const int ROWQ   = CAP / 4;    // 384 float4 per (tok,e) row
    int stride = gridDim.x * blockDim.x;
    for (int q = blockIdx.x * blockDim.x + threadIdx.x; q < TOTALQ; q += stride) {
        bool isdisp = q < HALFQ;
        int local = isdisp ? q : q - HALFQ;
        int tokE = local / ROWQ;           // tok*NE + e
        int p = (local - tokE * ROWQ) * 4; // element pos of lane .x
        int sp = slot_pos[tokE];
        float4 v = make_float4(0.f, 0.f, 0.f, 0.f);
        if (sp >= p && sp < p + 4) {
            float val = isdisp ? 1.0f : slot_val[tokE];
            ((float*)&v)[sp - p] = val;
        }
        *(float4*)(out + (size_t)q * 4) = v;
    }
}

// ---------------- host ----------------
extern "C" void kernel_launch(void* const* d_in, const int* in_sizes, int n_in,
                              void* d_out, int out_size, void* d_ws, size_t ws_size,
                              hipStream_t stream)
{
    const float* x  = (const float*)d_in[0];  // [2,2048,4096]
    const float* W1 = (const float*)d_in[1];  // [4096,4096]
    const float* b1 = (const float*)d_in[2];  // [4096]
    const float* W2 = (const float*)d_in[3];  // [4096,8]
    const float* b2 = (const float*)d_in[4];  // [8]
    float* out = (float*)d_out;

    // h staged in the combine region of d_out (overwritten later by fill).
    float* hbuf = out + COMB_OFF;             // 16,777,216 floats

    // ws layout (float offsets): logits 32768 | top2prob 8192 | top2idx 8192 |
    // partial 128 | slot_pos 32768 | slot_val 32768  (~460 KB)
    float* ws       = (float*)d_ws;
    float* logits   = ws;
    float* top2prob = ws + 32768;
    int*   top2idx  = (int*)(ws + 40960);
    float* partial  = ws + 49152;
    int*   slot_pos = (int*)(ws + 49280);
    float* slot_val = ws + 82048;

    // A: h = relu(x@W1 + b1)
    gemm_relu_kernel<<<dim3(HD / BN, NTOK / BM), 256, 0, stream>>>(x, W1, b1, hbuf);
    // B: logits = h@W2 + b2
    logits_kernel<<<NTOK, 256, 0, stream>>>(hbuf, W2, b2, logits);
    // C: softmax + top2 + renorm (+probs output, +partial sums)
    softmax_top2_kernel<<<NTOK / 256, 256, 0, stream>>>(
        logits, out + PROBS_OFF, top2prob, top2idx, partial);
    // D: capacity scan -> slot map, aux loss
    scan_dispatch_kernel<<<1, 256, 0, stream>>>(
        top2idx, top2prob, partial, slot_pos, slot_val, out + AUX_OFF);
    // E: streamed zero+scatter of dispatch & combine
    fill_outputs_kernel<<<4096, 256, 0, stream>>>(slot_pos, slot_val, out);
}

// Round 2
// 1988.147 us; speedup vs baseline: 1.1035x; 1.1035x over previous
//
#include <hip/hip_runtime.h>
#include <cmath>

// Problem constants (fixed by reference setup)
#define NTOK 4096            // B*S = 2*2048
#define HD   4096            // hidden dim
#define NE   8               // experts
#define CAP  1536            // int(B*S*1.5*2/8)
#define NSEL 8192            // NTOK * TOP_K
#define TAU  2e-3f           // near-tie gap threshold for exact fixup

// d_out layout (float element offsets)
#define COMB_OFF  50331648UL   // NTOK*NE*CAP
#define PROBS_OFF 100663296UL  // 2*NTOK*NE*CAP
#define AUX_OFF   100696064UL  // PROBS_OFF + NTOK*NE

typedef unsigned short ushort_t;
typedef short short8 __attribute__((ext_vector_type(8)));
typedef float floatx4 __attribute__((ext_vector_type(4)));

// ---- bf16 split helper: f = hi + lo, both bf16 (RNE) --------------------
__device__ __forceinline__ void split_bf16(float f, ushort_t& h, ushort_t& l) {
    unsigned int u = __float_as_uint(f);
    unsigned int r = u + 0x7FFFu + ((u >> 16) & 1u);
    h = (ushort_t)(r >> 16);
    float hf = __uint_as_float(((unsigned int)h) << 16);
    float lo = f - hf;
    unsigned int u2 = __float_as_uint(lo);
    unsigned int r2 = u2 + 0x7FFFu + ((u2 >> 16) & 1u);
    l = (ushort_t)(r2 >> 16);
}

// ---- async 16B global->LDS ----------------------------------------------
__device__ __forceinline__ void async_copy16(const void* g, void* l) {
    __builtin_amdgcn_global_load_lds(
        (const __attribute__((address_space(1))) unsigned int*)g,
        (__attribute__((address_space(3))) unsigned int*)l, 16, 0, 0);
}

// ---------------- Kernel 1: x -> xhi, xlo (bf16 bits) --------------------
__global__ __launch_bounds__(256) void convert_x_kernel(
    const float* __restrict__ x, ushort_t* __restrict__ xhi, ushort_t* __restrict__ xlo)
{
    size_t i = (size_t)blockIdx.x * 256 + threadIdx.x;   // float4 index
    float4 v = ((const float4*)x)[i];
    ushort4 h, l;
    split_bf16(v.x, h.x, l.x);
    split_bf16(v.y, h.y, l.y);
    split_bf16(v.z, h.z, l.z);
    split_bf16(v.w, h.w, l.w);
    ((ushort4*)xhi)[i] = h;
    ((ushort4*)xlo)[i] = l;
}

// ---------------- Kernel 2: W1 -> W1^T hi/lo (bf16 bits) -----------------
// 32x32 tiles through LDS; output is [n][k] (K-major, matches A layout).
__global__ __launch_bounds__(256) void convert_w1t_kernel(
    const float* __restrict__ W1, ushort_t* __restrict__ bthi, ushort_t* __restrict__ btlo)
{
    __shared__ float tile[32][33];
    const int bn = blockIdx.x;      // n tile
    const int bk = blockIdx.y;      // k tile
    const int t = threadIdx.x;
    const int r = t >> 3;           // 0..31
    const int c4 = (t & 7) * 4;     // 0,4,..28

    float4 v = *(const float4*)(W1 + (size_t)(bk * 32 + r) * HD + bn * 32 + c4);
    tile[r][c4 + 0] = v.x; tile[r][c4 + 1] = v.y;
    tile[r][c4 + 2] = v.z; tile[r][c4 + 3] = v.w;
    __syncthreads();

    ushort4 h4, l4;
    split_bf16(tile[c4 + 0][r], h4.x, l4.x);
    split_bf16(tile[c4 + 1][r], h4.y, l4.y);
    split_bf16(tile[c4 + 2][r], h4.z, l4.z);
    split_bf16(tile[c4 + 3][r], h4.w, l4.w);
    size_t o = (size_t)(bn * 32 + r) * HD + bk * 32 + c4;
    *(ushort4*)(bthi + o) = h4;
    *(ushort4*)(btlo + o) = l4;
}

// ---------------- Kernel 3: h = relu(x@W1 + b1) via split-bf16 MFMA ------
// 128x128 tile, 4 waves, each wave 64x64 (4x4 of 16x16x32), BK=32.
// LDS tiles stored in lane-order fragment layout: group g (16 rows) occupies
// bytes [g*1024, g*1024+1024), lane l's 16B at +l*16 == row g*16+(l&15),
// k-chunk (l>>4)*8. Staging dest order == global_load_lds forced order, and
// every frag read is one contiguous conflict-free ds_read_b128.
__global__ __launch_bounds__(256) void gemm_split_mfma(
    const ushort_t* __restrict__ Ahi, const ushort_t* __restrict__ Alo,  // x  [M][K]
    const ushort_t* __restrict__ Bhi, const ushort_t* __restrict__ Blo,  // W1^T [N][K]
    const float* __restrict__ bias,
    float* __restrict__ C)                                               // h [M][N]
{
    __shared__ __attribute__((aligned(16))) ushort_t lds[4][128 * 32];   // 32 KB

    const int tid  = threadIdx.x;
    const int wave = tid >> 6;
    const int lane = tid & 63;
    const int m0 = blockIdx.y * 128;
    const int n0 = blockIdx.x * 128;
    const int wr = (wave >> 1) * 64;   // wave row offset in tile
    const int wc = (wave & 1) * 64;    // wave col offset in tile

    floatx4 acc[4][4];
#pragma unroll
    for (int i = 0; i < 4; ++i)
#pragma unroll
        for (int j = 0; j < 4; ++j) acc[i][j] = (floatx4){0.f, 0.f, 0.f, 0.f};

    // staging: wave stages groups {2w, 2w+1} of each of the 4 tiles
    const int lrow = lane & 15;        // row within 16-row group
    const int lchk = lane >> 4;        // 16B chunk (8 bf16) within row
    const int gA = wave * 2;
    // element offsets into [4096]-wide K-major matrices (advance 32/step)
    size_t aOff0 = (size_t)(m0 + gA * 16 + lrow) * HD + lchk * 8;
    size_t aOff1 = aOff0 + 16 * HD;
    size_t bOff0 = (size_t)(n0 + gA * 16 + lrow) * HD + lchk * 8;
    size_t bOff1 = bOff0 + 16 * HD;
    ushort_t* ldsA0hi = &lds[0][gA * 512];  ushort_t* ldsA1hi = &lds[0][(gA + 1) * 512];
    ushort_t* ldsA0lo = &lds[1][gA * 512];  ushort_t* ldsA1lo = &lds[1][(gA + 1) * 512];
    ushort_t* ldsB0hi = &lds[2][gA * 512];  ushort_t* ldsB1hi = &lds[2][(gA + 1) * 512];
    ushort_t* ldsB0lo = &lds[3][gA * 512];  ushort_t* ldsB1lo = &lds[3][(gA + 1) * 512];

    const int fgA = (wr >> 4);         // first A frag group for this wave
    const int fgB = (wc >> 4);         // first B frag group

    for (int k0 = 0; k0 < HD; k0 += 32) {
        async_copy16(Ahi + aOff0 + k0, ldsA0hi);
        async_copy16(Ahi + aOff1 + k0, ldsA1hi);
        async_copy16(Alo + aOff0 + k0, ldsA0lo);
        async_copy16(Alo + aOff1 + k0, ldsA1lo);
        async_copy16(Bhi + bOff0 + k0, ldsB0hi);
        async_copy16(Bhi + bOff1 + k0, ldsB1hi);
        async_copy16(Blo + bOff0 + k0, ldsB0lo);
        async_copy16(Blo + bOff1 + k0, ldsB1lo);
        __syncthreads();

        short8 a_hi[4], a_lo[4], b_hi[4], b_lo[4];
#pragma unroll
        for (int i = 0; i < 4; ++i) {
            a_hi[i] = *(const short8*)&lds[0][(fgA + i) * 512 + lane * 8];
            a_lo[i] = *(const short8*)&lds[1][(fgA + i) * 512 + lane * 8];
            b_hi[i] = *(const short8*)&lds[2][(fgB + i) * 512 + lane * 8];
            b_lo[i] = *(const short8*)&lds[3][(fgB + i) * 512 + lane * 8];
        }
        __syncthreads();

#pragma unroll
        for (int i = 0; i < 4; ++i)
#pragma unroll
            for (int j = 0; j < 4; ++j) {
                acc[i][j] = __builtin_amdgcn_mfma_f32_16x16x32_bf16(a_hi[i], b_hi[j], acc[i][j], 0, 0, 0);
                acc[i][j] = __builtin_amdgcn_mfma_f32_16x16x32_bf16(a_hi[i], b_lo[j], acc[i][j], 0, 0, 0);
                acc[i][j] = __builtin_amdgcn_mfma_f32_16x16x32_bf16(a_lo[i], b_hi[j], acc[i][j], 0, 0, 0);
            }
    }

    // Epilogue: bias + relu; D[m][n]: n = lane&15, m = (lane>>4)*4 + r
    float bcol[4];
#pragma unroll
    for (int j = 0; j < 4; ++j) bcol[j] = bias[n0 + wc + j * 16 + (lane & 15)];
#pragma unroll
    for (int i = 0; i < 4; ++i) {
#pragma unroll
        for (int r = 0; r < 4; ++r) {
            int row = m0 + wr + i * 16 + (lane >> 4) * 4 + r;
            float* crow = C + (size_t)row * HD + n0 + wc + (lane & 15);
#pragma unroll
            for (int j = 0; j < 4; ++j) {
                float v = acc[i][j][r] + bcol[j];
                crow[j * 16] = v > 0.f ? v : 0.f;
            }
        }
    }
}

// ---------------- Kernel 4: logits = h @ W2 + b2 (fp32) ------------------
__global__ __launch_bounds__(256) void logits_kernel(
    const float* __restrict__ h, const float* __restrict__ W2,
    const float* __restrict__ b2, float* __restrict__ logits)
{
    const int t = blockIdx.x;
    const int tid = threadIdx.x;
    const float* hrow = h + (size_t)t * HD;

    float acc[NE];
#pragma unroll
    for (int e = 0; e < NE; ++e) acc[e] = 0.f;
    for (int f = tid; f < HD; f += 256) {
        float hv = hrow[f];
        float4 w0 = *(const float4*)(W2 + (size_t)f * NE);
        float4 w1 = *(const float4*)(W2 + (size_t)f * NE + 4);
        acc[0] += hv * w0.x; acc[1] += hv * w0.y; acc[2] += hv * w0.z; acc[3] += hv * w0.w;
        acc[4] += hv * w1.x; acc[5] += hv * w1.y; acc[6] += hv * w1.z; acc[7] += hv * w1.w;
    }
    __shared__ float red[256][NE];
#pragma unroll
    for (int e = 0; e < NE; ++e) red[tid][e] = acc[e];
    __syncthreads();
    for (int s = 128; s > 0; s >>= 1) {
        if (tid < s) {
#pragma unroll
            for (int e = 0; e < NE; ++e) red[tid][e] += red[tid + s][e];
        }
        __syncthreads();
    }
    if (tid < NE) logits[(size_t)t * NE + tid] = red[0][tid] + b2[tid];
}

// ---------------- Kernel 5: flag near-tie tokens (gap l2-l3 < TAU) -------
__global__ __launch_bounds__(256) void flag_kernel(
    const float* __restrict__ logits, int* __restrict__ flags)
{
    int t = blockIdx.x * 256 + threadIdx.x;
    float l[NE];
    *(float4*)(&l[0]) = *(const float4*)(logits + (size_t)t * NE);
    *(float4*)(&l[4]) = *(const float4*)(logits + (size_t)t * NE + 4);
    float a = -1e30f, b = -1e30f, c = -1e30f;
#pragma unroll
    for (int e = 0; e < NE; ++e) {
        float v = l[e];
        if (v > a) { c = b; b = a; a = v; }
        else if (v > b) { c = b; b = v; }
        else if (v > c) { c = v; }
    }
    flags[t] = (b - c < TAU) ? 1 : 0;
}

// ---------------- Kernel 6: exact fp32 logit recompute for flagged -------
__global__ __launch_bounds__(256) void fixup_kernel(
    const float* __restrict__ x, const float* __restrict__ W1,
    const float* __restrict__ b1, const float* __restrict__ W2,
    const float* __restrict__ b2, const int* __restrict__ flags,
    float* __restrict__ logits)
{
    __shared__ float red[256][NE];
    const int t = threadIdx.x;
    for (int tok = blockIdx.x; tok < NTOK; tok += gridDim.x) {
        if (!flags[tok]) continue;
        const float* xr = x + (size_t)tok * HD;
        float hsum[16];
#pragma unroll
        for (int fi = 0; fi < 16; ++fi) hsum[fi] = 0.f;
        for (int k = 0; k < HD; ++k) {
            float xv = xr[k];
            const float* wrow = W1 + (size_t)k * HD + t;
#pragma unroll
            for (int fi = 0; fi < 16; ++fi) hsum[fi] += xv * wrow[fi * 256];
        }
        float acc[NE];
#pragma unroll
        for (int e = 0; e < NE; ++e) acc[e] = 0.f;
#pragma unroll
        for (int fi = 0; fi < 16; ++fi) {
            int f = t + fi * 256;
            float hv = hsum[fi] + b1[f];
            hv = hv > 0.f ? hv : 0.f;
            float4 w0 = *(const float4*)(W2 + (size_t)f * NE);
            float4 w1 = *(const float4*)(W2 + (size_t)f * NE + 4);
            acc[0] += hv * w0.x; acc[1] += hv * w0.y; acc[2] += hv * w0.z; acc[3] += hv * w0.w;
            acc[4] += hv * w1.x; acc[5] += hv * w1.y; acc[6] += hv * w1.z; acc[7] += hv * w1.w;
        }
#pragma unroll
        for (int e = 0; e < NE; ++e) red[t][e] = acc[e];
        __syncthreads();
        for (int s = 128; s > 0; s >>= 1) {
            if (t < s) {
#pragma unroll
                for (int e = 0; e < NE; ++e) red[t][e] += red[t + s][e];
            }
            __syncthreads();
        }
        if (t < NE) logits[(size_t)tok * NE + t] = red[0][t] + b2[t];
        __syncthreads();
    }
}

// ---------------- Kernel 7: softmax + top2 + renorm + partial sums -------
__global__ __launch_bounds__(256) void softmax_top2_kernel(
    const float* __restrict__ logits, float* __restrict__ probs_out,
    float* __restrict__ top2prob, int* __restrict__ top2idx,
    float* __restrict__ partial)
{
    const int tid = threadIdx.x;
    const int t = blockIdx.x * 256 + tid;

    float l[NE];
    *(float4*)(&l[0]) = *(const float4*)(logits + (size_t)t * NE);
    *(float4*)(&l[4]) = *(const float4*)(logits + (size_t)t * NE + 4);

    float mx = l[0];
#pragma unroll
    for (int e = 1; e < NE; ++e) mx = fmaxf(mx, l[e]);
    float p[NE], sum = 0.f;
#pragma unroll
    for (int e = 0; e < NE; ++e) { p[e] = __expf(l[e] - mx); sum += p[e]; }
    float inv = 1.f / sum;
#pragma unroll
    for (int e = 0; e < NE; ++e) p[e] *= inv;

#pragma unroll
    for (int e = 0; e < NE; ++e) probs_out[(size_t)t * NE + e] = p[e];

    float b1v = -1e30f, b2v = -1e30f;
    int i1 = 0, i2 = 0;
#pragma unroll
    for (int e = 0; e < NE; ++e) {
        float v = l[e];
        if (v > b1v) { b2v = b1v; i2 = i1; b1v = v; i1 = e; }
        else if (v > b2v) { b2v = v; i2 = e; }
    }
    float p1 = 0.f, p2 = 0.f;
#pragma unroll
    for (int e = 0; e < NE; ++e) { if (e == i1) p1 = p[e]; if (e == i2) p2 = p[e]; }
    float s = p1 + p2 + 1e-8f;
    top2prob[2 * t]     = p1 / s;
    top2prob[2 * t + 1] = p2 / s;
    top2idx[2 * t]      = i1;
    top2idx[2 * t + 1]  = i2;

    __shared__ float red[256][NE];
#pragma unroll
    for (int e = 0; e < NE; ++e) red[tid][e] = p[e];
    __syncthreads();
    for (int sdx = 128; sdx > 0; sdx >>= 1) {
        if (tid < sdx) {
#pragma unroll
            for (int e = 0; e < NE; ++e) red[tid][e] += red[tid + sdx][e];
        }
        __syncthreads();
    }
    if (tid < NE) partial[blockIdx.x * NE + tid] = red[0][tid];
}

// ---------------- Kernel 8: sequential capacity scan + slot map + aux ----
__global__ __launch_bounds__(256) void scan_dispatch_kernel(
    const int* __restrict__ top2idx, const float* __restrict__ top2prob,
    const float* __restrict__ partial, int* __restrict__ slot_pos,
    float* __restrict__ slot_val, float* __restrict__ aux_out)
{
    const int tid = threadIdx.x;
    const int ITEMS = NSEL / 256;

    for (int i = tid; i < NTOK * NE; i += 256) { slot_pos[i] = -1; slot_val[i] = 0.f; }

    int cnt[NE];
#pragma unroll
    for (int e = 0; e < NE; ++e) cnt[e] = 0;
    const int base = tid * ITEMS;
    for (int j = 0; j < ITEMS; ++j) {
        int v = top2idx[base + j];
#pragma unroll
        for (int e = 0; e < NE; ++e) cnt[e] += (v == e);
    }

    __shared__ int scnt[256][NE];
    __shared__ int tot[NE];
#pragma unroll
    for (int e = 0; e < NE; ++e) scnt[tid][e] = cnt[e];
    __syncthreads();

    if (tid < NE) {
        int run = 0;
        for (int i = 0; i < 256; ++i) {
            int c = scnt[i][tid];
            scnt[i][tid] = run;
            run += c;
        }
        tot[tid] = run;
    }
    __syncthreads();

    int off[NE];
#pragma unroll
    for (int e = 0; e < NE; ++e) off[e] = scnt[tid][e];
    for (int j = 0; j < ITEMS; ++j) {
        int item = base + j;
        int v = top2idx[item];
        int pos = 0;
#pragma unroll
        for (int e = 0; e < NE; ++e) { if (v == e) { pos = off[e]; off[e]++; } }
        if (pos < CAP) {
            int tok = item >> 1;
            slot_pos[tok * NE + v] = pos;
            slot_val[tok * NE + v] = top2prob[item];
        }
    }

    if (tid == 0) {
        float aux = 0.f;
#pragma unroll
        for (int e = 0; e < NE; ++e) {
            float pp = 0.f;
            for (int b = 0; b < 16; ++b) pp += partial[b * NE + e];
            aux += (pp / (float)NTOK) * ((float)tot[e] / (float)NSEL);
        }
        aux_out[0] = aux * (float)NE;
    }
}

// ---------------- Kernel 9: fused zero-fill + scatter --------------------
__global__ __launch_bounds__(256) void fill_outputs_kernel(
    const int* __restrict__ slot_pos, const float* __restrict__ slot_val,
    float* __restrict__ out)
{
    const int TOTALQ = 25165824;   // 2*NTOK*NE*CAP / 4
    const int HALFQ  = 12582912;
    const int ROWQ   = CAP / 4;
    int stride = gridDim.x * blockDim.x;
    for (int q = blockIdx.x * blockDim.x + threadIdx.x; q < TOTALQ; q += stride) {
        bool isdisp = q < HALFQ;
        int local = isdisp ? q : q - HALFQ;
        int tokE = local / ROWQ;
        int p = (local - tokE * ROWQ) * 4;
        int sp = slot_pos[tokE];
        float4 v = make_float4(0.f, 0.f, 0.f, 0.f);
        if (sp >= p && sp < p + 4) {
            float val = isdisp ? 1.0f : slot_val[tokE];
            ((float*)&v)[sp - p] = val;
        }
        *(float4*)(out + (size_t)q * 4) = v;
    }
}

// ---------------- host ---------------------------------------------------
extern "C" void kernel_launch(void* const* d_in, const int* in_sizes, int n_in,
                              void* d_out, int out_size, void* d_ws, size_t ws_size,
                              hipStream_t stream)
{
    const float* x  = (const float*)d_in[0];
    const float* W1 = (const float*)d_in[1];
    const float* b1 = (const float*)d_in[2];
    const float* W2 = (const float*)d_in[3];
    const float* b2 = (const float*)d_in[4];
    float* out = (float*)d_out;

    // Staging in d_out (overwritten by fill_outputs at the end):
    // dispatch region: xhi | xlo | w1thi | w1tlo (bf16 bits, 134 MB total)
    ushort_t* xhi   = (ushort_t*)(out);
    ushort_t* xlo   = (ushort_t*)(out + 8388608);
    ushort_t* w1thi = (ushort_t*)(out + 16777216);
    ushort_t* w1tlo = (ushort_t*)(out + 25165824);
    // combine region: h (fp32, 67 MB)
    float* hbuf = out + COMB_OFF;

    // ws layout (float offsets): logits 32768 | top2prob 8192 | top2idx 8192
    // | partial 128 | slot_pos 32768 | slot_val 32768 | flags 4096
    float* ws       = (float*)d_ws;
    float* logits   = ws;
    float* top2prob = ws + 32768;
    int*   top2idx  = (int*)(ws + 40960);
    float* partial  = ws + 49152;
    int*   slot_pos = (int*)(ws + 49280);
    float* slot_val = ws + 82048;
    int*   flags    = (int*)(ws + 114816);

    convert_x_kernel<<<16384, 256, 0, stream>>>(x, xhi, xlo);
    convert_w1t_kernel<<<dim3(128, 128), 256, 0, stream>>>(W1, w1thi, w1tlo);
    gemm_split_mfma<<<dim3(32, 32), 256, 0, stream>>>(xhi, xlo, w1thi, w1tlo, b1, hbuf);
    logits_kernel<<<NTOK, 256, 0, stream>>>(hbuf, W2, b2, logits);
    flag_kernel<<<16, 256, 0, stream>>>(logits, flags);
    fixup_kernel<<<256, 256, 0, stream>>>(x, W1, b1, W2, b2, flags, logits);
    softmax_top2_kernel<<<16, 256, 0, stream>>>(logits, out + PROBS_OFF, top2prob, top2idx, partial);
    scan_dispatch_kernel<<<1, 256, 0, stream>>>(top2idx, top2prob, partial, slot_pos, slot_val, out + AUX_OFF);
    fill_outputs_kernel<<<4096, 256, 0, stream>>>(slot_pos, slot_val, out);
}

// Round 3
// 1146.790 us; speedup vs baseline: 1.9131x; 1.7337x over previous
//
#include <hip/hip_runtime.h>
#include <cmath>

// Problem constants (fixed by reference setup)
#define NTOK 4096            // B*S = 2*2048
#define HD   4096            // hidden dim
#define NE   8               // experts
#define CAP  1536            // int(B*S*1.5*2/8)
#define NSEL 8192            // NTOK * TOP_K
#define TAU  1e-3f           // near-tie gap threshold for exact fixup
#define MAXFLAG 64
#define GSIZE 16             // flagged tokens processed per W1 pass

// d_out layout (float element offsets)
#define COMB_OFF  50331648UL   // NTOK*NE*CAP
#define PROBS_OFF 100663296UL  // 2*NTOK*NE*CAP
#define AUX_OFF   100696064UL  // PROBS_OFF + NTOK*NE
#define HFLAG_OFF 33554432UL   // in dispatch region, after bf16 staging

typedef unsigned short ushort_t;
typedef short short8 __attribute__((ext_vector_type(8)));
typedef float floatx4 __attribute__((ext_vector_type(4)));

// ---- bf16 split helper: f = hi + lo, both bf16 (RNE) --------------------
__device__ __forceinline__ void split_bf16(float f, ushort_t& h, ushort_t& l) {
    unsigned int u = __float_as_uint(f);
    unsigned int r = u + 0x7FFFu + ((u >> 16) & 1u);
    h = (ushort_t)(r >> 16);
    float hf = __uint_as_float(((unsigned int)h) << 16);
    float lo = f - hf;
    unsigned int u2 = __float_as_uint(lo);
    unsigned int r2 = u2 + 0x7FFFu + ((u2 >> 16) & 1u);
    l = (ushort_t)(r2 >> 16);
}

// ---- async 16B global->LDS ----------------------------------------------
__device__ __forceinline__ void async_copy16(const void* g, void* l) {
    __builtin_amdgcn_global_load_lds(
        (const __attribute__((address_space(1))) unsigned int*)g,
        (__attribute__((address_space(3))) unsigned int*)l, 16, 0, 0);
}

// ---------------- Kernel 1: x -> xhi, xlo (bf16 bits) --------------------
__global__ __launch_bounds__(256) void convert_x_kernel(
    const float* __restrict__ x, ushort_t* __restrict__ xhi, ushort_t* __restrict__ xlo)
{
    size_t i = (size_t)blockIdx.x * 256 + threadIdx.x;   // float4 index
    float4 v = ((const float4*)x)[i];
    ushort4 h, l;
    split_bf16(v.x, h.x, l.x);
    split_bf16(v.y, h.y, l.y);
    split_bf16(v.z, h.z, l.z);
    split_bf16(v.w, h.w, l.w);
    ((ushort4*)xhi)[i] = h;
    ((ushort4*)xlo)[i] = l;
}

// ---------------- Kernel 2: W1 -> W1^T hi/lo (bf16 bits) -----------------
__global__ __launch_bounds__(256) void convert_w1t_kernel(
    const float* __restrict__ W1, ushort_t* __restrict__ bthi, ushort_t* __restrict__ btlo)
{
    __shared__ float tile[32][33];
    const int bn = blockIdx.x;      // n tile
    const int bk = blockIdx.y;      // k tile
    const int t = threadIdx.x;
    const int r = t >> 3;           // 0..31
    const int c4 = (t & 7) * 4;     // 0,4,..28

    float4 v = *(const float4*)(W1 + (size_t)(bk * 32 + r) * HD + bn * 32 + c4);
    tile[r][c4 + 0] = v.x; tile[r][c4 + 1] = v.y;
    tile[r][c4 + 2] = v.z; tile[r][c4 + 3] = v.w;
    __syncthreads();

    ushort4 h4, l4;
    split_bf16(tile[c4 + 0][r], h4.x, l4.x);
    split_bf16(tile[c4 + 1][r], h4.y, l4.y);
    split_bf16(tile[c4 + 2][r], h4.z, l4.z);
    split_bf16(tile[c4 + 3][r], h4.w, l4.w);
    size_t o = (size_t)(bn * 32 + r) * HD + bk * 32 + c4;
    *(ushort4*)(bthi + o) = h4;
    *(ushort4*)(btlo + o) = l4;
}

// ---------------- Kernel 3: h = relu(x@W1 + b1) via split-bf16 MFMA ------
__global__ __launch_bounds__(256) void gemm_split_mfma(
    const ushort_t* __restrict__ Ahi, const ushort_t* __restrict__ Alo,  // x  [M][K]
    const ushort_t* __restrict__ Bhi, const ushort_t* __restrict__ Blo,  // W1^T [N][K]
    const float* __restrict__ bias,
    float* __restrict__ C)                                               // h [M][N]
{
    __shared__ __attribute__((aligned(16))) ushort_t lds[4][128 * 32];   // 32 KB

    const int tid  = threadIdx.x;
    const int wave = tid >> 6;
    const int lane = tid & 63;
    const int m0 = blockIdx.y * 128;
    const int n0 = blockIdx.x * 128;
    const int wr = (wave >> 1) * 64;   // wave row offset in tile
    const int wc = (wave & 1) * 64;    // wave col offset in tile

    floatx4 acc[4][4];
#pragma unroll
    for (int i = 0; i < 4; ++i)
#pragma unroll
        for (int j = 0; j < 4; ++j) acc[i][j] = (floatx4){0.f, 0.f, 0.f, 0.f};

    const int lrow = lane & 15;        // row within 16-row group
    const int lchk = lane >> 4;        // 16B chunk (8 bf16) within row
    const int gA = wave * 2;
    size_t aOff0 = (size_t)(m0 + gA * 16 + lrow) * HD + lchk * 8;
    size_t aOff1 = aOff0 + 16 * HD;
    size_t bOff0 = (size_t)(n0 + gA * 16 + lrow) * HD + lchk * 8;
    size_t bOff1 = bOff0 + 16 * HD;
    ushort_t* ldsA0hi = &lds[0][gA * 512];  ushort_t* ldsA1hi = &lds[0][(gA + 1) * 512];
    ushort_t* ldsA0lo = &lds[1][gA * 512];  ushort_t* ldsA1lo = &lds[1][(gA + 1) * 512];
    ushort_t* ldsB0hi = &lds[2][gA * 512];  ushort_t* ldsB1hi = &lds[2][(gA + 1) * 512];
    ushort_t* ldsB0lo = &lds[3][gA * 512];  ushort_t* ldsB1lo = &lds[3][(gA + 1) * 512];

    const int fgA = (wr >> 4);
    const int fgB = (wc >> 4);

    for (int k0 = 0; k0 < HD; k0 += 32) {
        async_copy16(Ahi + aOff0 + k0, ldsA0hi);
        async_copy16(Ahi + aOff1 + k0, ldsA1hi);
        async_copy16(Alo + aOff0 + k0, ldsA0lo);
        async_copy16(Alo + aOff1 + k0, ldsA1lo);
        async_copy16(Bhi + bOff0 + k0, ldsB0hi);
        async_copy16(Bhi + bOff1 + k0, ldsB1hi);
        async_copy16(Blo + bOff0 + k0, ldsB0lo);
        async_copy16(Blo + bOff1 + k0, ldsB1lo);
        __syncthreads();

        short8 a_hi[4], a_lo[4], b_hi[4], b_lo[4];
#pragma unroll
        for (int i = 0; i < 4; ++i) {
            a_hi[i] = *(const short8*)&lds[0][(fgA + i) * 512 + lane * 8];
            a_lo[i] = *(const short8*)&lds[1][(fgA + i) * 512 + lane * 8];
            b_hi[i] = *(const short8*)&lds[2][(fgB + i) * 512 + lane * 8];
            b_lo[i] = *(const short8*)&lds[3][(fgB + i) * 512 + lane * 8];
        }
        __syncthreads();

#pragma unroll
        for (int i = 0; i < 4; ++i)
#pragma unroll
            for (int j = 0; j < 4; ++j) {
                acc[i][j] = __builtin_amdgcn_mfma_f32_16x16x32_bf16(a_hi[i], b_hi[j], acc[i][j], 0, 0, 0);
                acc[i][j] = __builtin_amdgcn_mfma_f32_16x16x32_bf16(a_hi[i], b_lo[j], acc[i][j], 0, 0, 0);
                acc[i][j] = __builtin_amdgcn_mfma_f32_16x16x32_bf16(a_lo[i], b_hi[j], acc[i][j], 0, 0, 0);
            }
    }

    float bcol[4];
#pragma unroll
    for (int j = 0; j < 4; ++j) bcol[j] = bias[n0 + wc + j * 16 + (lane & 15)];
#pragma unroll
    for (int i = 0; i < 4; ++i) {
#pragma unroll
        for (int r = 0; r < 4; ++r) {
            int row = m0 + wr + i * 16 + (lane >> 4) * 4 + r;
            float* crow = C + (size_t)row * HD + n0 + wc + (lane & 15);
#pragma unroll
            for (int j = 0; j < 4; ++j) {
                float v = acc[i][j][r] + bcol[j];
                crow[j * 16] = v > 0.f ? v : 0.f;
            }
        }
    }
}

// ---------------- Kernel 4: logits = h @ W2 + b2 (fp32) ------------------
__global__ __launch_bounds__(256) void logits_kernel(
    const float* __restrict__ h, const float* __restrict__ W2,
    const float* __restrict__ b2, float* __restrict__ logits)
{
    const int t = blockIdx.x;
    const int tid = threadIdx.x;
    const float* hrow = h + (size_t)t * HD;

    float acc[NE];
#pragma unroll
    for (int e = 0; e < NE; ++e) acc[e] = 0.f;
    for (int f = tid; f < HD; f += 256) {
        float hv = hrow[f];
        float4 w0 = *(const float4*)(W2 + (size_t)f * NE);
        float4 w1 = *(const float4*)(W2 + (size_t)f * NE + 4);
        acc[0] += hv * w0.x; acc[1] += hv * w0.y; acc[2] += hv * w0.z; acc[3] += hv * w0.w;
        acc[4] += hv * w1.x; acc[5] += hv * w1.y; acc[6] += hv * w1.z; acc[7] += hv * w1.w;
    }
    __shared__ float red[256][NE];
#pragma unroll
    for (int e = 0; e < NE; ++e) red[tid][e] = acc[e];
    __syncthreads();
    for (int s = 128; s > 0; s >>= 1) {
        if (tid < s) {
#pragma unroll
            for (int e = 0; e < NE; ++e) red[tid][e] += red[tid + s][e];
        }
        __syncthreads();
    }
    if (tid < NE) logits[(size_t)t * NE + tid] = red[0][tid] + b2[tid];
}

// ---------------- Kernel 5a: zero hflag + count --------------------------
__global__ __launch_bounds__(256) void zero_fix_kernel(
    float* __restrict__ hflag, int* __restrict__ count)
{
    int i = blockIdx.x * 256 + threadIdx.x;     // 65536 threads, 1 float4 each
    ((float4*)hflag)[i] = make_float4(0.f, 0.f, 0.f, 0.f);
    if (i == 0) *count = 0;
}

// ---------------- Kernel 5b: flag near-ties, compact list ----------------
__global__ __launch_bounds__(256) void flag_compact_kernel(
    const float* __restrict__ logits, int* __restrict__ count, int* __restrict__ list)
{
    int t = blockIdx.x * 256 + threadIdx.x;     // grid 16
    float l[NE];
    *(float4*)(&l[0]) = *(const float4*)(logits + (size_t)t * NE);
    *(float4*)(&l[4]) = *(const float4*)(logits + (size_t)t * NE + 4);
    float a = -1e30f, b = -1e30f, c = -1e30f;
#pragma unroll
    for (int e = 0; e < NE; ++e) {
        float v = l[e];
        if (v > a) { c = b; b = a; a = v; }
        else if (v > b) { c = b; b = v; }
        else if (v > c) { c = v; }
    }
    if (b - c < TAU) {
        int p = atomicAdd(count, 1);
        if (p < MAXFLAG) list[p] = t;
    }
}

// ---------------- Kernel 6a: batched exact pre-activation h for flagged --
// grid (64 f-chunks, 4 k-splits), 256 threads. One shared pass over W1 per
// group of 16 flagged tokens; atomicAdd partials into hflag[slot][f].
__global__ __launch_bounds__(256) void fixup_stageA(
    const float* __restrict__ x, const float* __restrict__ W1,
    const int* __restrict__ count_p, const int* __restrict__ list,
    float* __restrict__ hflag)
{
    __shared__ float xs[GSIZE][256];          // 16 KB
    __shared__ float red[4][GSIZE][64];       // 16 KB
    const int tid = threadIdx.x;
    const int fl  = tid & 63;                 // f lane
    const int kg  = tid >> 6;                 // k group 0..3
    const int f   = blockIdx.x * 64 + fl;
    const int kbase = blockIdx.y * 1024;
    int count = *count_p;
    if (count > MAXFLAG) count = MAXFLAG;

    for (int g = 0; g * GSIZE < count; ++g) {
        const int gbase = g * GSIZE;
        int ntok = count - gbase; if (ntok > GSIZE) ntok = GSIZE;

        float acc[GSIZE];
#pragma unroll
        for (int t = 0; t < GSIZE; ++t) acc[t] = 0.f;

        for (int kb = 0; kb < 1024; kb += 256) {
            __syncthreads();
            for (int i = tid; i < ntok * 256; i += 256) {
                int t = i >> 8, kk = i & 255;
                xs[t][kk] = x[(size_t)list[gbase + t] * HD + kbase + kb + kk];
            }
            __syncthreads();
            for (int j = 0; j < 64; ++j) {
                int kk = kg * 64 + j;
                float w = W1[(size_t)(kbase + kb + kk) * HD + f];
#pragma unroll
                for (int t = 0; t < GSIZE; ++t) acc[t] += xs[t][kk] * w;
            }
        }
        __syncthreads();
#pragma unroll
        for (int t = 0; t < GSIZE; ++t) red[kg][t][fl] = acc[t];
        __syncthreads();
        if (kg == 0) {
            for (int t = 0; t < ntok; ++t) {
                float v = red[0][t][fl] + red[1][t][fl] + red[2][t][fl] + red[3][t][fl];
                atomicAdd(&hflag[(size_t)(gbase + t) * HD + f], v);
            }
        }
        __syncthreads();
    }
}

// ---------------- Kernel 6b: exact logits for flagged tokens -------------
__global__ __launch_bounds__(256) void fixup_stageB(
    const float* __restrict__ hflag, const float* __restrict__ b1,
    const float* __restrict__ W2, const float* __restrict__ b2,
    const int* __restrict__ count_p, const int* __restrict__ list,
    float* __restrict__ logits)
{
    int count = *count_p;
    if (count > MAXFLAG) count = MAXFLAG;
    const int b = blockIdx.x;
    if (b >= count) return;
    const int tok = list[b];
    const int tid = threadIdx.x;

    float acc[NE];
#pragma unroll
    for (int e = 0; e < NE; ++e) acc[e] = 0.f;
    for (int f = tid; f < HD; f += 256) {
        float hv = hflag[(size_t)b * HD + f] + b1[f];
        hv = hv > 0.f ? hv : 0.f;
        float4 w0 = *(const float4*)(W2 + (size_t)f * NE);
        float4 w1 = *(const float4*)(W2 + (size_t)f * NE + 4);
        acc[0] += hv * w0.x; acc[1] += hv * w0.y; acc[2] += hv * w0.z; acc[3] += hv * w0.w;
        acc[4] += hv * w1.x; acc[5] += hv * w1.y; acc[6] += hv * w1.z; acc[7] += hv * w1.w;
    }
    __shared__ float red[256][NE];
#pragma unroll
    for (int e = 0; e < NE; ++e) red[tid][e] = acc[e];
    __syncthreads();
    for (int s = 128; s > 0; s >>= 1) {
        if (tid < s) {
#pragma unroll
            for (int e = 0; e < NE; ++e) red[tid][e] += red[tid + s][e];
        }
        __syncthreads();
    }
    if (tid < NE) logits[(size_t)tok * NE + tid] = red[0][tid] + b2[tid];
}

// ---------------- Kernel 7: softmax + top2 + renorm + partial sums -------
__global__ __launch_bounds__(256) void softmax_top2_kernel(
    const float* __restrict__ logits, float* __restrict__ probs_out,
    float* __restrict__ top2prob, int* __restrict__ top2idx,
    float* __restrict__ partial)
{
    const int tid = threadIdx.x;
    const int t = blockIdx.x * 256 + tid;

    float l[NE];
    *(float4*)(&l[0]) = *(const float4*)(logits + (size_t)t * NE);
    *(float4*)(&l[4]) = *(const float4*)(logits + (size_t)t * NE + 4);

    float mx = l[0];
#pragma unroll
    for (int e = 1; e < NE; ++e) mx = fmaxf(mx, l[e]);
    float p[NE], sum = 0.f;
#pragma unroll
    for (int e = 0; e < NE; ++e) { p[e] = __expf(l[e] - mx); sum += p[e]; }
    float inv = 1.f / sum;
#pragma unroll
    for (int e = 0; e < NE; ++e) p[e] *= inv;

#pragma unroll
    for (int e = 0; e < NE; ++e) probs_out[(size_t)t * NE + e] = p[e];

    float b1v = -1e30f, b2v = -1e30f;
    int i1 = 0, i2 = 0;
#pragma unroll
    for (int e = 0; e < NE; ++e) {
        float v = l[e];
        if (v > b1v) { b2v = b1v; i2 = i1; b1v = v; i1 = e; }
        else if (v > b2v) { b2v = v; i2 = e; }
    }
    float p1 = 0.f, p2 = 0.f;
#pragma unroll
    for (int e = 0; e < NE; ++e) { if (e == i1) p1 = p[e]; if (e == i2) p2 = p[e]; }
    float s = p1 + p2 + 1e-8f;
    top2prob[2 * t]     = p1 / s;
    top2prob[2 * t + 1] = p2 / s;
    top2idx[2 * t]      = i1;
    top2idx[2 * t + 1]  = i2;

    __shared__ float red[256][NE];
#pragma unroll
    for (int e = 0; e < NE; ++e) red[tid][e] = p[e];
    __syncthreads();
    for (int sdx = 128; sdx > 0; sdx >>= 1) {
        if (tid < sdx) {
#pragma unroll
            for (int e = 0; e < NE; ++e) red[tid][e] += red[tid + sdx][e];
        }
        __syncthreads();
    }
    if (tid < NE) partial[blockIdx.x * NE + tid] = red[0][tid];
}

// ---------------- Kernel 8: sequential capacity scan + slot map + aux ----
__global__ __launch_bounds__(256) void scan_dispatch_kernel(
    const int* __restrict__ top2idx, const float* __restrict__ top2prob,
    const float* __restrict__ partial, int* __restrict__ slot_pos,
    float* __restrict__ slot_val, float* __restrict__ aux_out)
{
    const int tid = threadIdx.x;
    const int ITEMS = NSEL / 256;

    for (int i = tid; i < NTOK * NE; i += 256) { slot_pos[i] = -1; slot_val[i] = 0.f; }

    int cnt[NE];
#pragma unroll
    for (int e = 0; e < NE; ++e) cnt[e] = 0;
    const int base = tid * ITEMS;
    for (int j = 0; j < ITEMS; ++j) {
        int v = top2idx[base + j];
#pragma unroll
        for (int e = 0; e < NE; ++e) cnt[e] += (v == e);
    }

    __shared__ int scnt[256][NE];
    __shared__ int tot[NE];
#pragma unroll
    for (int e = 0; e < NE; ++e) scnt[tid][e] = cnt[e];
    __syncthreads();

    if (tid < NE) {
        int run = 0;
        for (int i = 0; i < 256; ++i) {
            int c = scnt[i][tid];
            scnt[i][tid] = run;
            run += c;
        }
        tot[tid] = run;
    }
    __syncthreads();

    int off[NE];
#pragma unroll
    for (int e = 0; e < NE; ++e) off[e] = scnt[tid][e];
    for (int j = 0; j < ITEMS; ++j) {
        int item = base + j;
        int v = top2idx[item];
        int pos = 0;
#pragma unroll
        for (int e = 0; e < NE; ++e) { if (v == e) { pos = off[e]; off[e]++; } }
        if (pos < CAP) {
            int tok = item >> 1;
            slot_pos[tok * NE + v] = pos;
            slot_val[tok * NE + v] = top2prob[item];
        }
    }

    if (tid == 0) {
        float aux = 0.f;
#pragma unroll
        for (int e = 0; e < NE; ++e) {
            float pp = 0.f;
            for (int b = 0; b < 16; ++b) pp += partial[b * NE + e];
            aux += (pp / (float)NTOK) * ((float)tot[e] / (float)NSEL);
        }
        aux_out[0] = aux * (float)NE;
    }
}

// ---------------- Kernel 9: fused zero-fill + scatter --------------------
__global__ __launch_bounds__(256) void fill_outputs_kernel(
    const int* __restrict__ slot_pos, const float* __restrict__ slot_val,
    float* __restrict__ out)
{
    const int TOTALQ = 25165824;   // 2*NTOK*NE*CAP / 4
    const int HALFQ  = 12582912;
    const int ROWQ   = CAP / 4;
    int stride = gridDim.x * blockDim.x;
    for (int q = blockIdx.x * blockDim.x + threadIdx.x; q < TOTALQ; q += stride) {
        bool isdisp = q < HALFQ;
        int local = isdisp ? q : q - HALFQ;
        int tokE = local / ROWQ;
        int p = (local - tokE * ROWQ) * 4;
        int sp = slot_pos[tokE];
        float4 v = make_float4(0.f, 0.f, 0.f, 0.f);
        if (sp >= p && sp < p + 4) {
            float val = isdisp ? 1.0f : slot_val[tokE];
            ((float*)&v)[sp - p] = val;
        }
        *(float4*)(out + (size_t)q * 4) = v;
    }
}

// ---------------- host ---------------------------------------------------
extern "C" void kernel_launch(void* const* d_in, const int* in_sizes, int n_in,
                              void* d_out, int out_size, void* d_ws, size_t ws_size,
                              hipStream_t stream)
{
    const float* x  = (const float*)d_in[0];
    const float* W1 = (const float*)d_in[1];
    const float* b1 = (const float*)d_in[2];
    const float* W2 = (const float*)d_in[3];
    const float* b2 = (const float*)d_in[4];
    float* out = (float*)d_out;

    // Staging in d_out (overwritten by fill_outputs at the end):
    // dispatch region: xhi | xlo | w1thi | w1tlo (bf16 bits) | hflag (fp32)
    ushort_t* xhi   = (ushort_t*)(out);
    ushort_t* xlo   = (ushort_t*)(out + 8388608);
    ushort_t* w1thi = (ushort_t*)(out + 16777216);
    ushort_t* w1tlo = (ushort_t*)(out + 25165824);
    float*    hflag = out + HFLAG_OFF;        // MAXFLAG*HD floats (1 MB)
    // combine region: h (fp32, 67 MB)
    float* hbuf = out + COMB_OFF;

    // ws layout (float offsets): logits 32768 | top2prob 8192 | top2idx 8192
    // | partial 128 | slot_pos 32768 | slot_val 32768 | count 1 | list 64
    float* ws       = (float*)d_ws;
    float* logits   = ws;
    float* top2prob = ws + 32768;
    int*   top2idx  = (int*)(ws + 40960);
    float* partial  = ws + 49152;
    int*   slot_pos = (int*)(ws + 49280);
    float* slot_val = ws + 82048;
    int*   count    = (int*)(ws + 114816);
    int*   list     = (int*)(ws + 114817);

    convert_x_kernel<<<16384, 256, 0, stream>>>(x, xhi, xlo);
    convert_w1t_kernel<<<dim3(128, 128), 256, 0, stream>>>(W1, w1thi, w1tlo);
    gemm_split_mfma<<<dim3(32, 32), 256, 0, stream>>>(xhi, xlo, w1thi, w1tlo, b1, hbuf);
    logits_kernel<<<NTOK, 256, 0, stream>>>(hbuf, W2, b2, logits);
    zero_fix_kernel<<<256, 256, 0, stream>>>(hflag, count);
    flag_compact_kernel<<<16, 256, 0, stream>>>(logits, count, list);
    fixup_stageA<<<dim3(64, 4), 256, 0, stream>>>(x, W1, count, list, hflag);
    fixup_stageB<<<MAXFLAG, 256, 0, stream>>>(hflag, b1, W2, b2, count, list, logits);
    softmax_top2_kernel<<<16, 256, 0, stream>>>(logits, out + PROBS_OFF, top2prob, top2idx, partial);
    scan_dispatch_kernel<<<1, 256, 0, stream>>>(top2idx, top2prob, partial, slot_pos, slot_val, out + AUX_OFF);
    fill_outputs_kernel<<<4096, 256, 0, stream>>>(slot_pos, slot_val, out);
}

// Round 4
// 1064.671 us; speedup vs baseline: 2.0606x; 1.0771x over previous
//
#include <hip/hip_runtime.h>
#include <cmath>

// Problem constants (fixed by reference setup)
#define NTOK 4096            // B*S = 2*2048
#define HD   4096            // hidden dim
#define NE   8               // experts
#define CAP  1536            // int(B*S*1.5*2/8)
#define NSEL 8192            // NTOK * TOP_K
#define TAU  1e-3f           // near-tie gap threshold for exact fixup
#define MAXFLAG 64
#define GSIZE 16             // flagged tokens processed per W1 pass

// d_out layout (float element offsets)
#define COMB_OFF  50331648UL   // NTOK*NE*CAP
#define PROBS_OFF 100663296UL  // 2*NTOK*NE*CAP
#define AUX_OFF   100696064UL  // PROBS_OFF + NTOK*NE
#define HFLAG_OFF 33554432UL   // in dispatch region, after bf16 staging

typedef unsigned short ushort_t;
typedef short short8 __attribute__((ext_vector_type(8)));
typedef ushort_t ushort8v __attribute__((ext_vector_type(8)));
typedef float floatx16 __attribute__((ext_vector_type(16)));

// ---- bf16 split helper: f = hi + lo, both bf16 (RNE) --------------------
__device__ __forceinline__ void split_bf16(float f, ushort_t& h, ushort_t& l) {
    unsigned int u = __float_as_uint(f);
    unsigned int r = u + 0x7FFFu + ((u >> 16) & 1u);
    h = (ushort_t)(r >> 16);
    float hf = __uint_as_float(((unsigned int)h) << 16);
    float lo = f - hf;
    unsigned int u2 = __float_as_uint(lo);
    unsigned int r2 = u2 + 0x7FFFu + ((u2 >> 16) & 1u);
    l = (ushort_t)(r2 >> 16);
}

// ---- async 16B global->LDS ----------------------------------------------
__device__ __forceinline__ void async_copy16(const void* g, void* l) {
    __builtin_amdgcn_global_load_lds(
        (const __attribute__((address_space(1))) unsigned int*)g,
        (__attribute__((address_space(3))) unsigned int*)l, 16, 0, 0);
}

// ---------------- Kernel 1: x -> xhi, xlo (bf16 bits) --------------------
__global__ __launch_bounds__(256) void convert_x_kernel(
    const float* __restrict__ x, ushort_t* __restrict__ xhi, ushort_t* __restrict__ xlo)
{
    size_t i = (size_t)blockIdx.x * 256 + threadIdx.x;   // float4 index
    float4 v = ((const float4*)x)[i];
    ushort4 h, l;
    split_bf16(v.x, h.x, l.x);
    split_bf16(v.y, h.y, l.y);
    split_bf16(v.z, h.z, l.z);
    split_bf16(v.w, h.w, l.w);
    ((ushort4*)xhi)[i] = h;
    ((ushort4*)xlo)[i] = l;
}

// ---------------- Kernel 2: W1 -> W1^T hi/lo, 64x64 tiles ----------------
// Writes 128 B contiguous segments (8 threads x ushort8 per row).
__global__ __launch_bounds__(256) void convert_w1t64_kernel(
    const float* __restrict__ W1, ushort_t* __restrict__ bthi, ushort_t* __restrict__ btlo)
{
    __shared__ float tile[64][65];
    const int bn = blockIdx.x, bk = blockIdx.y, t = threadIdx.x;
#pragma unroll
    for (int it = 0; it < 4; ++it) {
        int row = it * 16 + (t >> 4);
        int c4  = (t & 15) * 4;
        float4 v = *(const float4*)(W1 + (size_t)(bk * 64 + row) * HD + bn * 64 + c4);
        tile[row][c4 + 0] = v.x; tile[row][c4 + 1] = v.y;
        tile[row][c4 + 2] = v.z; tile[row][c4 + 3] = v.w;
    }
    __syncthreads();
#pragma unroll
    for (int p = 0; p < 2; ++p) {
        int n  = p * 32 + (t >> 3);
        int kc = (t & 7) * 8;
        ushort8v h8, l8;
#pragma unroll
        for (int j = 0; j < 8; ++j) {
            ushort_t hh, ll;
            split_bf16(tile[kc + j][n], hh, ll);
            h8[j] = hh; l8[j] = ll;
        }
        size_t o = (size_t)(bn * 64 + n) * HD + bk * 64 + kc;
        *(ushort8v*)(bthi + o) = h8;
        *(ushort8v*)(btlo + o) = l8;
    }
}

// ---------------- Kernel 3: h = relu(x@W1 + b1), 32x32x16 MFMA -----------
// Block 256x128, 4 waves (2x2), wave tile 128x64 = 4x2 blocks of 32x32.
// LDS (48 KB): Ahi[8 grp x 1024us] | Alo | Bhi[4 grp] | Blo, kc-major inside
// each 32-row group so frag reads are contiguous ds_read_b128 at lane*16.
__global__ __launch_bounds__(256, 2) void gemm32_kernel(
    const ushort_t* __restrict__ Ahi, const ushort_t* __restrict__ Alo,  // x [M][K]
    const ushort_t* __restrict__ Bhi, const ushort_t* __restrict__ Blo,  // W1^T [N][K]
    const float* __restrict__ bias,
    float* __restrict__ C)                                               // h [M][N]
{
    __shared__ __attribute__((aligned(16))) ushort_t lds[24576];  // 48 KB
    // ushort offsets: Ahi 0, Alo 8192, Bhi 16384, Blo 20480; group stride 1024

    const int tid  = threadIdx.x;
    const int wave = tid >> 6;
    const int lane = tid & 63;
    const int l31  = lane & 31;
    const int lh   = lane >> 5;
    const int m0 = blockIdx.y * 256;
    const int n0 = blockIdx.x * 128;
    const int wm = wave >> 1;          // 0..1 : wave m-half (128 rows)
    const int wn = wave & 1;           // 0..1 : wave n-half (64 cols)

    floatx16 acc[4][2];
#pragma unroll
    for (int mi = 0; mi < 4; ++mi)
#pragma unroll
        for (int ni = 0; ni < 2; ++ni)
#pragma unroll
            for (int r = 0; r < 16; ++r) acc[mi][ni][r] = 0.f;

    // staging sources: wave stages A groups {2w,2w+1}, B group {w}
    const size_t aRow0 = (size_t)(m0 + 2 * wave * 32 + l31) * HD;
    const size_t aRow1 = aRow0 + 32 * HD;
    const size_t bRow  = (size_t)(n0 + wave * 32 + l31) * HD;
    const int kI0 = lh * 8;            // instr 0 k source offset
    const int kI1 = 16 + lh * 8;       // instr 1

    ushort_t* dA0 = lds + 2 * wave * 1024;
    ushort_t* dA1 = lds + (2 * wave + 1) * 1024;
    ushort_t* dB  = lds + 16384 + wave * 1024;

    for (int k0 = 0; k0 < HD; k0 += 32) {
        async_copy16(Ahi + aRow0 + k0 + kI0, dA0);
        async_copy16(Ahi + aRow0 + k0 + kI1, dA0 + 512);
        async_copy16(Ahi + aRow1 + k0 + kI0, dA1);
        async_copy16(Ahi + aRow1 + k0 + kI1, dA1 + 512);
        async_copy16(Alo + aRow0 + k0 + kI0, dA0 + 8192);
        async_copy16(Alo + aRow0 + k0 + kI1, dA0 + 8192 + 512);
        async_copy16(Alo + aRow1 + k0 + kI0, dA1 + 8192);
        async_copy16(Alo + aRow1 + k0 + kI1, dA1 + 8192 + 512);
        async_copy16(Bhi + bRow + k0 + kI0, dB);
        async_copy16(Bhi + bRow + k0 + kI1, dB + 512);
        async_copy16(Blo + bRow + k0 + kI0, dB + 4096);
        async_copy16(Blo + bRow + k0 + kI1, dB + 4096 + 512);
        __syncthreads();

#pragma unroll
        for (int h = 0; h < 2; ++h) {
            short8 ah[4], al[4], bh[2], bl[2];
#pragma unroll
            for (int mi = 0; mi < 4; ++mi) {
                ah[mi] = *(const short8*)&lds[(wm * 4 + mi) * 1024 + h * 512 + lane * 8];
                al[mi] = *(const short8*)&lds[8192 + (wm * 4 + mi) * 1024 + h * 512 + lane * 8];
            }
#pragma unroll
            for (int ni = 0; ni < 2; ++ni) {
                bh[ni] = *(const short8*)&lds[16384 + (wn * 2 + ni) * 1024 + h * 512 + lane * 8];
                bl[ni] = *(const short8*)&lds[20480 + (wn * 2 + ni) * 1024 + h * 512 + lane * 8];
            }
#pragma unroll
            for (int mi = 0; mi < 4; ++mi)
#pragma unroll
                for (int ni = 0; ni < 2; ++ni) {
                    acc[mi][ni] = __builtin_amdgcn_mfma_f32_32x32x16_bf16(ah[mi], bh[ni], acc[mi][ni], 0, 0, 0);
                    acc[mi][ni] = __builtin_amdgcn_mfma_f32_32x32x16_bf16(ah[mi], bl[ni], acc[mi][ni], 0, 0, 0);
                    acc[mi][ni] = __builtin_amdgcn_mfma_f32_32x32x16_bf16(al[mi], bh[ni], acc[mi][ni], 0, 0, 0);
                }
        }
        __syncthreads();
    }

    // Epilogue: bias + relu. C/D map: col = l31, row = (r&3)+8*(r>>2)+4*lh
    const int nc0 = n0 + wn * 64 + l31;
    float b1v0 = bias[nc0], b1v1 = bias[nc0 + 32];
#pragma unroll
    for (int mi = 0; mi < 4; ++mi) {
#pragma unroll
        for (int r = 0; r < 16; ++r) {
            int row = m0 + wm * 128 + mi * 32 + (r & 3) + 8 * (r >> 2) + 4 * lh;
            float* crow = C + (size_t)row * HD + nc0;
            float v0 = acc[mi][0][r] + b1v0;
            float v1 = acc[mi][1][r] + b1v1;
            crow[0]  = v0 > 0.f ? v0 : 0.f;
            crow[32] = v1 > 0.f ? v1 : 0.f;
        }
    }
}

// ---------------- Kernel 4: logits = h @ W2 + b2 (fp32) ------------------
__global__ __launch_bounds__(256) void logits_kernel(
    const float* __restrict__ h, const float* __restrict__ W2,
    const float* __restrict__ b2, float* __restrict__ logits)
{
    const int t = blockIdx.x;
    const int tid = threadIdx.x;
    const float* hrow = h + (size_t)t * HD;

    float acc[NE];
#pragma unroll
    for (int e = 0; e < NE; ++e) acc[e] = 0.f;
    for (int f = tid; f < HD; f += 256) {
        float hv = hrow[f];
        float4 w0 = *(const float4*)(W2 + (size_t)f * NE);
        float4 w1 = *(const float4*)(W2 + (size_t)f * NE + 4);
        acc[0] += hv * w0.x; acc[1] += hv * w0.y; acc[2] += hv * w0.z; acc[3] += hv * w0.w;
        acc[4] += hv * w1.x; acc[5] += hv * w1.y; acc[6] += hv * w1.z; acc[7] += hv * w1.w;
    }
    __shared__ float red[256][NE];
#pragma unroll
    for (int e = 0; e < NE; ++e) red[tid][e] = acc[e];
    __syncthreads();
    for (int s = 128; s > 0; s >>= 1) {
        if (tid < s) {
#pragma unroll
            for (int e = 0; e < NE; ++e) red[tid][e] += red[tid + s][e];
        }
        __syncthreads();
    }
    if (tid < NE) logits[(size_t)t * NE + tid] = red[0][tid] + b2[tid];
}

// ---------------- Kernel 5a: zero hflag + count --------------------------
__global__ __launch_bounds__(256) void zero_fix_kernel(
    float* __restrict__ hflag, int* __restrict__ count)
{
    int i = blockIdx.x * 256 + threadIdx.x;     // 65536 threads, 1 float4 each
    ((float4*)hflag)[i] = make_float4(0.f, 0.f, 0.f, 0.f);
    if (i == 0) *count = 0;
}

// ---------------- Kernel 5b: flag near-ties, compact list ----------------
__global__ __launch_bounds__(256) void flag_compact_kernel(
    const float* __restrict__ logits, int* __restrict__ count, int* __restrict__ list)
{
    int t = blockIdx.x * 256 + threadIdx.x;     // grid 16
    float l[NE];
    *(float4*)(&l[0]) = *(const float4*)(logits + (size_t)t * NE);
    *(float4*)(&l[4]) = *(const float4*)(logits + (size_t)t * NE + 4);
    float a = -1e30f, b = -1e30f, c = -1e30f;
#pragma unroll
    for (int e = 0; e < NE; ++e) {
        float v = l[e];
        if (v > a) { c = b; b = a; a = v; }
        else if (v > b) { c = b; b = v; }
        else if (v > c) { c = v; }
    }
    if (b - c < TAU) {
        int p = atomicAdd(count, 1);
        if (p < MAXFLAG) list[p] = t;
    }
}

// ---------------- Kernel 6a: batched exact pre-activation h for flagged --
__global__ __launch_bounds__(256) void fixup_stageA(
    const float* __restrict__ x, const float* __restrict__ W1,
    const int* __restrict__ count_p, const int* __restrict__ list,
    float* __restrict__ hflag)
{
    __shared__ float xs[GSIZE][256];          // 16 KB
    __shared__ float red[4][GSIZE][64];       // 16 KB
    const int tid = threadIdx.x;
    const int fl  = tid & 63;                 // f lane
    const int kg  = tid >> 6;                 // k group 0..3
    const int f   = blockIdx.x * 64 + fl;
    const int kbase = blockIdx.y * 1024;
    int count = *count_p;
    if (count > MAXFLAG) count = MAXFLAG;

    for (int g = 0; g * GSIZE < count; ++g) {
        const int gbase = g * GSIZE;
        int ntok = count - gbase; if (ntok > GSIZE) ntok = GSIZE;

        float acc[GSIZE];
#pragma unroll
        for (int t = 0; t < GSIZE; ++t) acc[t] = 0.f;

        for (int kb = 0; kb < 1024; kb += 256) {
            __syncthreads();
            for (int i = tid; i < ntok * 256; i += 256) {
                int t = i >> 8, kk = i & 255;
                xs[t][kk] = x[(size_t)list[gbase + t] * HD + kbase + kb + kk];
            }
            __syncthreads();
            for (int j = 0; j < 64; ++j) {
                int kk = kg * 64 + j;
                float w = W1[(size_t)(kbase + kb + kk) * HD + f];
#pragma unroll
                for (int t = 0; t < GSIZE; ++t) acc[t] += xs[t][kk] * w;
            }
        }
        __syncthreads();
#pragma unroll
        for (int t = 0; t < GSIZE; ++t) red[kg][t][fl] = acc[t];
        __syncthreads();
        if (kg == 0) {
            for (int t = 0; t < ntok; ++t) {
                float v = red[0][t][fl] + red[1][t][fl] + red[2][t][fl] + red[3][t][fl];
                atomicAdd(&hflag[(size_t)(gbase + t) * HD + f], v);
            }
        }
        __syncthreads();
    }
}

// ---------------- Kernel 6b: exact logits for flagged tokens -------------
__global__ __launch_bounds__(256) void fixup_stageB(
    const float* __restrict__ hflag, const float* __restrict__ b1,
    const float* __restrict__ W2, const float* __restrict__ b2,
    const int* __restrict__ count_p, const int* __restrict__ list,
    float* __restrict__ logits)
{
    int count = *count_p;
    if (count > MAXFLAG) count = MAXFLAG;
    const int b = blockIdx.x;
    if (b >= count) return;
    const int tok = list[b];
    const int tid = threadIdx.x;

    float acc[NE];
#pragma unroll
    for (int e = 0; e < NE; ++e) acc[e] = 0.f;
    for (int f = tid; f < HD; f += 256) {
        float hv = hflag[(size_t)b * HD + f] + b1[f];
        hv = hv > 0.f ? hv : 0.f;
        float4 w0 = *(const float4*)(W2 + (size_t)f * NE);
        float4 w1 = *(const float4*)(W2 + (size_t)f * NE + 4);
        acc[0] += hv * w0.x; acc[1] += hv * w0.y; acc[2] += hv * w0.z; acc[3] += hv * w0.w;
        acc[4] += hv * w1.x; acc[5] += hv * w1.y; acc[6] += hv * w1.z; acc[7] += hv * w1.w;
    }
    __shared__ float red[256][NE];
#pragma unroll
    for (int e = 0; e < NE; ++e) red[tid][e] = acc[e];
    __syncthreads();
    for (int s = 128; s > 0; s >>= 1) {
        if (tid < s) {
#pragma unroll
            for (int e = 0; e < NE; ++e) red[tid][e] += red[tid + s][e];
        }
        __syncthreads();
    }
    if (tid < NE) logits[(size_t)tok * NE + tid] = red[0][tid] + b2[tid];
}

// ---------------- Kernel 7: softmax + top2 + renorm + partial sums -------
__global__ __launch_bounds__(256) void softmax_top2_kernel(
    const float* __restrict__ logits, float* __restrict__ probs_out,
    float* __restrict__ top2prob, int* __restrict__ top2idx,
    float* __restrict__ partial)
{
    const int tid = threadIdx.x;
    const int t = blockIdx.x * 256 + tid;

    float l[NE];
    *(float4*)(&l[0]) = *(const float4*)(logits + (size_t)t * NE);
    *(float4*)(&l[4]) = *(const float4*)(logits + (size_t)t * NE + 4);

    float mx = l[0];
#pragma unroll
    for (int e = 1; e < NE; ++e) mx = fmaxf(mx, l[e]);
    float p[NE], sum = 0.f;
#pragma unroll
    for (int e = 0; e < NE; ++e) { p[e] = __expf(l[e] - mx); sum += p[e]; }
    float inv = 1.f / sum;
#pragma unroll
    for (int e = 0; e < NE; ++e) p[e] *= inv;

#pragma unroll
    for (int e = 0; e < NE; ++e) probs_out[(size_t)t * NE + e] = p[e];

    float b1v = -1e30f, b2v = -1e30f;
    int i1 = 0, i2 = 0;
#pragma unroll
    for (int e = 0; e < NE; ++e) {
        float v = l[e];
        if (v > b1v) { b2v = b1v; i2 = i1; b1v = v; i1 = e; }
        else if (v > b2v) { b2v = v; i2 = e; }
    }
    float p1 = 0.f, p2 = 0.f;
#pragma unroll
    for (int e = 0; e < NE; ++e) { if (e == i1) p1 = p[e]; if (e == i2) p2 = p[e]; }
    float s = p1 + p2 + 1e-8f;
    top2prob[2 * t]     = p1 / s;
    top2prob[2 * t + 1] = p2 / s;
    top2idx[2 * t]      = i1;
    top2idx[2 * t + 1]  = i2;

    __shared__ float red[256][NE];
#pragma unroll
    for (int e = 0; e < NE; ++e) red[tid][e] = p[e];
    __syncthreads();
    for (int sdx = 128; sdx > 0; sdx >>= 1) {
        if (tid < sdx) {
#pragma unroll
            for (int e = 0; e < NE; ++e) red[tid][e] += red[tid + sdx][e];
        }
        __syncthreads();
    }
    if (tid < NE) partial[blockIdx.x * NE + tid] = red[0][tid];
}

// ---------------- Kernel 8: sequential capacity scan + slot map + aux ----
__global__ __launch_bounds__(256) void scan_dispatch_kernel(
    const int* __restrict__ top2idx, const float* __restrict__ top2prob,
    const float* __restrict__ partial, int* __restrict__ slot_pos,
    float* __restrict__ slot_val, float* __restrict__ aux_out)
{
    const int tid = threadIdx.x;
    const int ITEMS = NSEL / 256;

    for (int i = tid; i < NTOK * NE; i += 256) { slot_pos[i] = -1; slot_val[i] = 0.f; }

    int cnt[NE];
#pragma unroll
    for (int e = 0; e < NE; ++e) cnt[e] = 0;
    const int base = tid * ITEMS;
    for (int j = 0; j < ITEMS; ++j) {
        int v = top2idx[base + j];
#pragma unroll
        for (int e = 0; e < NE; ++e) cnt[e] += (v == e);
    }

    __shared__ int scnt[256][NE];
    __shared__ int tot[NE];
#pragma unroll
    for (int e = 0; e < NE; ++e) scnt[tid][e] = cnt[e];
    __syncthreads();

    if (tid < NE) {
        int run = 0;
        for (int i = 0; i < 256; ++i) {
            int c = scnt[i][tid];
            scnt[i][tid] = run;
            run += c;
        }
        tot[tid] = run;
    }
    __syncthreads();

    int off[NE];
#pragma unroll
    for (int e = 0; e < NE; ++e) off[e] = scnt[tid][e];
    for (int j = 0; j < ITEMS; ++j) {
        int item = base + j;
        int v = top2idx[item];
        int pos = 0;
#pragma unroll
        for (int e = 0; e < NE; ++e) { if (v == e) { pos = off[e]; off[e]++; } }
        if (pos < CAP) {
            int tok = item >> 1;
            slot_pos[tok * NE + v] = pos;
            slot_val[tok * NE + v] = top2prob[item];
        }
    }

    if (tid == 0) {
        float aux = 0.f;
#pragma unroll
        for (int e = 0; e < NE; ++e) {
            float pp = 0.f;
            for (int b = 0; b < 16; ++b) pp += partial[b * NE + e];
            aux += (pp / (float)NTOK) * ((float)tot[e] / (float)NSEL);
        }
        aux_out[0] = aux * (float)NE;
    }
}

// ---------------- Kernel 9: fused zero-fill + scatter --------------------
__global__ __launch_bounds__(256) void fill_outputs_kernel(
    const int* __restrict__ slot_pos, const float* __restrict__ slot_val,
    float* __restrict__ out)
{
    const int TOTALQ = 25165824;   // 2*NTOK*NE*CAP / 4
    const int HALFQ  = 12582912;
    const int ROWQ   = CAP / 4;
    int stride = gridDim.x * blockDim.x;
    for (int q = blockIdx.x * blockDim.x + threadIdx.x; q < TOTALQ; q += stride) {
        bool isdisp = q < HALFQ;
        int local = isdisp ? q : q - HALFQ;
        int tokE = local / ROWQ;
        int p = (local - tokE * ROWQ) * 4;
        int sp = slot_pos[tokE];
        float4 v = make_float4(0.f, 0.f, 0.f, 0.f);
        if (sp >= p && sp < p + 4) {
            float val = isdisp ? 1.0f : slot_val[tokE];
            ((float*)&v)[sp - p] = val;
        }
        *(float4*)(out + (size_t)q * 4) = v;
    }
}

// ---------------- host ---------------------------------------------------
extern "C" void kernel_launch(void* const* d_in, const int* in_sizes, int n_in,
                              void* d_out, int out_size, void* d_ws, size_t ws_size,
                              hipStream_t stream)
{
    const float* x  = (const float*)d_in[0];
    const float* W1 = (const float*)d_in[1];
    const float* b1 = (const float*)d_in[2];
    const float* W2 = (const float*)d_in[3];
    const float* b2 = (const float*)d_in[4];
    float* out = (float*)d_out;

    // Staging in d_out (overwritten by fill_outputs at the end):
    ushort_t* xhi   = (ushort_t*)(out);
    ushort_t* xlo   = (ushort_t*)(out + 8388608);
    ushort_t* w1thi = (ushort_t*)(out + 16777216);
    ushort_t* w1tlo = (ushort_t*)(out + 25165824);
    float*    hflag = out + HFLAG_OFF;        // MAXFLAG*HD floats (1 MB)
    float* hbuf = out + COMB_OFF;             // h (fp32, 67 MB) in combine region

    // ws layout (float offsets)
    float* ws       = (float*)d_ws;
    float* logits   = ws;
    float* top2prob = ws + 32768;
    int*   top2idx  = (int*)(ws + 40960);
    float* partial  = ws + 49152;
    int*   slot_pos = (int*)(ws + 49280);
    float* slot_val = ws + 82048;
    int*   count    = (int*)(ws + 114816);
    int*   list     = (int*)(ws + 114817);

    convert_x_kernel<<<16384, 256, 0, stream>>>(x, xhi, xlo);
    convert_w1t64_kernel<<<dim3(64, 64), 256, 0, stream>>>(W1, w1thi, w1tlo);
    gemm32_kernel<<<dim3(32, 16), 256, 0, stream>>>(xhi, xlo, w1thi, w1tlo, b1, hbuf);
    logits_kernel<<<NTOK, 256, 0, stream>>>(hbuf, W2, b2, logits);
    zero_fix_kernel<<<256, 256, 0, stream>>>(hflag, count);
    flag_compact_kernel<<<16, 256, 0, stream>>>(logits, count, list);
    fixup_stageA<<<dim3(64, 4), 256, 0, stream>>>(x, W1, count, list, hflag);
    fixup_stageB<<<MAXFLAG, 256, 0, stream>>>(hflag, b1, W2, b2, count, list, logits);
    softmax_top2_kernel<<<16, 256, 0, stream>>>(logits, out + PROBS_OFF, top2prob, top2idx, partial);
    scan_dispatch_kernel<<<1, 256, 0, stream>>>(top2idx, top2prob, partial, slot_pos, slot_val, out + AUX_OFF);
    fill_outputs_kernel<<<4096, 256, 0, stream>>>(slot_pos, slot_val, out);
}

// Round 6
// 1013.403 us; speedup vs baseline: 2.1649x; 1.0506x over previous
//
#include <hip/hip_runtime.h>
#include <cmath>

// Problem constants (fixed by reference setup)
#define NTOK 4096            // B*S = 2*2048
#define HD   4096            // hidden dim
#define NE   8               // experts
#define CAP  1536            // int(B*S*1.5*2/8)
#define NSEL 8192            // NTOK * TOP_K
#define TAU  1e-3f           // near-tie gap threshold for exact fixup
#define MAXFLAG 64
#define GSIZE 16             // flagged tokens processed per W1 pass

// d_out layout (float element offsets)
#define COMB_OFF  50331648UL   // NTOK*NE*CAP
#define PROBS_OFF 100663296UL  // 2*NTOK*NE*CAP
#define AUX_OFF   100696064UL  // PROBS_OFF + NTOK*NE
#define HFLAG_OFF 33554432UL   // in dispatch region, after bf16 staging

typedef unsigned short ushort_t;
typedef short short8 __attribute__((ext_vector_type(8)));
typedef ushort_t ushort8v __attribute__((ext_vector_type(8)));
typedef float floatx16 __attribute__((ext_vector_type(16)));

// Panel format (both A and B operands):
//   [group g (32 rows/cols)][kstep ks (32 k)][2048 bytes]
// Within a 2 KB block, 16B chunk u (u=0..127): h=u>>6, l=u&63, r=l&31,
// oh=l>>5 -> holds elements (row r, k = h*16 + oh*8 + j), j=0..7.
// This is exactly the LDS fragment image: ds_read addr = h*1024 + lane*16.
// Staging: lane l sources chunk u=l (h=0 half) / u=64+l (h=1 half) -> each
// global_load_lds instruction reads one contiguous 1 KB burst.

// ---- bf16 split helper: f = hi + lo, both bf16 (RNE) --------------------
__device__ __forceinline__ void split_bf16(float f, ushort_t& h, ushort_t& l) {
    unsigned int u = __float_as_uint(f);
    unsigned int r = u + 0x7FFFu + ((u >> 16) & 1u);
    h = (ushort_t)(r >> 16);
    float hf = __uint_as_float(((unsigned int)h) << 16);
    float lo = f - hf;
    unsigned int u2 = __float_as_uint(lo);
    unsigned int r2 = u2 + 0x7FFFu + ((u2 >> 16) & 1u);
    l = (ushort_t)(r2 >> 16);
}

// ---- async 16B global->LDS (gsrc is PER-LANE; lds dest = base+lane*16) --
__device__ __forceinline__ void async_copy16(const void* g, void* l) {
    __builtin_amdgcn_global_load_lds(
        (const __attribute__((address_space(1))) unsigned int*)g,
        (__attribute__((address_space(3))) unsigned int*)l, 16, 0, 0);
}

// ---------------- Kernel 1: x -> hi/lo panels ----------------------------
// grid (128 g, 32 q); block covers rows g*32..+32, k = q*128..+128.
__global__ __launch_bounds__(256) void convert_x_panel(
    const float* __restrict__ x, ushort_t* __restrict__ hip_, ushort_t* __restrict__ lop_)
{
    __shared__ float xs[32 * 128];      // 16 KB, row-major [r][k_local]
    const int g = blockIdx.x, q = blockIdx.y, t = threadIdx.x;
#pragma unroll
    for (int i = 0; i < 4; ++i) {
        int idx = i * 256 + t;          // float4 index, 0..1023
        int row = idx >> 5, c4 = (idx & 31) * 4;
        float4 v = *(const float4*)(x + (size_t)(g * 32 + row) * HD + q * 128 + c4);
        *(float4*)(&xs[row * 128 + c4]) = v;
    }
    __syncthreads();
#pragma unroll
    for (int it = 0; it < 2; ++it) {
        int c = it * 256 + t;           // chunk id 0..511
        int s = c >> 7, u = c & 127;
        int h = u >> 6, l = u & 63, r = l & 31, oh = l >> 5;
        int kl = s * 32 + h * 16 + oh * 8;
        ushort8v h8, l8;
#pragma unroll
        for (int j = 0; j < 8; ++j) {
            ushort_t hh, ll;
            split_bf16(xs[r * 128 + kl + j], hh, ll);
            h8[j] = hh; l8[j] = ll;
        }
        size_t off = ((size_t)(g * 128 + q * 4 + s)) * 1024 + u * 8;
        *(ushort8v*)(hip_ + off) = h8;
        *(ushort8v*)(lop_ + off) = l8;
    }
}

// ---------------- Kernel 2: W1 -> W1^T hi/lo panels ----------------------
// grid (128 gn, 32 q); covers n = gn*32..+32, k = q*128..+128 (transpose).
__global__ __launch_bounds__(256) void convert_w1_panel(
    const float* __restrict__ W1, ushort_t* __restrict__ hip_, ushort_t* __restrict__ lop_)
{
    __shared__ float ws[32 * 129];      // [n_local][k_local], padded
    const int gn = blockIdx.x, q = blockIdx.y, t = threadIdx.x;
#pragma unroll
    for (int i = 0; i < 4; ++i) {
        int idx = i * 256 + t;          // 0..1023
        int kr = idx >> 3, c4 = (idx & 7) * 4;
        float4 v = *(const float4*)(W1 + (size_t)(q * 128 + kr) * HD + gn * 32 + c4);
        ws[(c4 + 0) * 129 + kr] = v.x;
        ws[(c4 + 1) * 129 + kr] = v.y;
        ws[(c4 + 2) * 129 + kr] = v.z;
        ws[(c4 + 3) * 129 + kr] = v.w;
    }
    __syncthreads();
#pragma unroll
    for (int it = 0; it < 2; ++it) {
        int c = it * 256 + t;
        int s = c >> 7, u = c & 127;
        int h = u >> 6, l = u & 63, r = l & 31, oh = l >> 5;
        int kl = s * 32 + h * 16 + oh * 8;
        ushort8v h8, l8;
#pragma unroll
        for (int j = 0; j < 8; ++j) {
            ushort_t hh, ll;
            split_bf16(ws[r * 129 + kl + j], hh, ll);
            h8[j] = hh; l8[j] = ll;
        }
        size_t off = ((size_t)(gn * 128 + q * 4 + s)) * 1024 + u * 8;
        *(ushort8v*)(hip_ + off) = h8;
        *(ushort8v*)(lop_ + off) = l8;
    }
}

// ---------------- Kernel 3: h = relu(x@W1 + b1), 32x32x16 MFMA -----------
// Block 256x128, 4 waves (2x2), wave tile 128x64 = 4x2 blocks of 32x32.
// Staging reads contiguous 1 KB per async instr from panels (per-lane src!).
__global__ __launch_bounds__(256, 2) void gemm32_kernel(
    const ushort_t* __restrict__ Ahi, const ushort_t* __restrict__ Alo,  // x panels
    const ushort_t* __restrict__ Bhi, const ushort_t* __restrict__ Blo,  // W1^T panels
    const float* __restrict__ bias,
    float* __restrict__ C)                                               // h [M][N]
{
    __shared__ __attribute__((aligned(16))) ushort_t lds[24576];  // 48 KB
    // ushort offsets: Ahi 0 (8 grp x 1024), Alo 8192, Bhi 16384 (4 grp), Blo 20480

    const int tid  = threadIdx.x;
    const int wave = tid >> 6;
    const int lane = tid & 63;
    const int l31  = lane & 31;
    const int lh   = lane >> 5;
    const int m0 = blockIdx.y * 256;
    const int n0 = blockIdx.x * 128;
    const int wm = wave >> 1;          // wave m-half (128 rows)
    const int wn = wave & 1;           // wave n-half (64 cols)

    floatx16 acc[4][2];
#pragma unroll
    for (int mi = 0; mi < 4; ++mi)
#pragma unroll
        for (int ni = 0; ni < 2; ++ni)
#pragma unroll
            for (int r = 0; r < 16; ++r) acc[mi][ni][r] = 0.f;

    // panel sources: wave stages A groups {2w,2w+1}, B group {w}
    const int gmA0 = blockIdx.y * 8 + 2 * wave;
    const int gnB  = blockIdx.x * 4 + wave;
    const int lsrc = lane * 8;         // per-lane source offset (16 B/lane)
    const ushort_t* srcA0hi = Ahi + (size_t)gmA0 * 128 * 1024 + lsrc;
    const ushort_t* srcA1hi = srcA0hi + 128 * 1024;
    const ushort_t* srcA0lo = Alo + (size_t)gmA0 * 128 * 1024 + lsrc;
    const ushort_t* srcA1lo = srcA0lo + 128 * 1024;
    const ushort_t* srcBhi  = Bhi + (size_t)gnB * 128 * 1024 + lsrc;
    const ushort_t* srcBlo  = Blo + (size_t)gnB * 128 * 1024 + lsrc;

    ushort_t* dA0 = lds + 2 * wave * 1024;
    ushort_t* dA1 = lds + (2 * wave + 1) * 1024;
    ushort_t* dB  = lds + 16384 + wave * 1024;

    for (int ks = 0; ks < 128; ++ks) {
        const size_t po = (size_t)ks * 1024;   // ushort offset of this 2KB block
        async_copy16(srcA0hi + po,       dA0);
        async_copy16(srcA0hi + po + 512, dA0 + 512);
        async_copy16(srcA1hi + po,       dA1);
        async_copy16(srcA1hi + po + 512, dA1 + 512);
        async_copy16(srcA0lo + po,       dA0 + 8192);
        async_copy16(srcA0lo + po + 512, dA0 + 8192 + 512);
        async_copy16(srcA1lo + po,       dA1 + 8192);
        async_copy16(srcA1lo + po + 512, dA1 + 8192 + 512);
        async_copy16(srcBhi + po,        dB);
        async_copy16(srcBhi + po + 512,  dB + 512);
        async_copy16(srcBlo + po,        dB + 4096);
        async_copy16(srcBlo + po + 512,  dB + 4096 + 512);
        __syncthreads();

#pragma unroll
        for (int h = 0; h < 2; ++h) {
            short8 ah[4], al[4], bh[2], bl[2];
#pragma unroll
            for (int mi = 0; mi < 4; ++mi) {
                ah[mi] = *(const short8*)&lds[(wm * 4 + mi) * 1024 + h * 512 + lane * 8];
                al[mi] = *(const short8*)&lds[8192 + (wm * 4 + mi) * 1024 + h * 512 + lane * 8];
            }
#pragma unroll
            for (int ni = 0; ni < 2; ++ni) {
                bh[ni] = *(const short8*)&lds[16384 + (wn * 2 + ni) * 1024 + h * 512 + lane * 8];
                bl[ni] = *(const short8*)&lds[20480 + (wn * 2 + ni) * 1024 + h * 512 + lane * 8];
            }
#pragma unroll
            for (int mi = 0; mi < 4; ++mi)
#pragma unroll
                for (int ni = 0; ni < 2; ++ni) {
                    acc[mi][ni] = __builtin_amdgcn_mfma_f32_32x32x16_bf16(ah[mi], bh[ni], acc[mi][ni], 0, 0, 0);
                    acc[mi][ni] = __builtin_amdgcn_mfma_f32_32x32x16_bf16(ah[mi], bl[ni], acc[mi][ni], 0, 0, 0);
                    acc[mi][ni] = __builtin_amdgcn_mfma_f32_32x32x16_bf16(al[mi], bh[ni], acc[mi][ni], 0, 0, 0);
                }
        }
        __syncthreads();
    }

    // Epilogue: bias + relu. C/D map: col = l31, row = (r&3)+8*(r>>2)+4*lh
    const int nc0 = n0 + wn * 64 + l31;
    float b1v0 = bias[nc0], b1v1 = bias[nc0 + 32];
#pragma unroll
    for (int mi = 0; mi < 4; ++mi) {
#pragma unroll
        for (int r = 0; r < 16; ++r) {
            int row = m0 + wm * 128 + mi * 32 + (r & 3) + 8 * (r >> 2) + 4 * lh;
            float* crow = C + (size_t)row * HD + nc0;
            float v0 = acc[mi][0][r] + b1v0;
            float v1 = acc[mi][1][r] + b1v1;
            crow[0]  = v0 > 0.f ? v0 : 0.f;
            crow[32] = v1 > 0.f ? v1 : 0.f;
        }
    }
}

// ---------------- Kernel 4: logits = h @ W2 + b2 (fp32) ------------------
__global__ __launch_bounds__(256) void logits_kernel(
    const float* __restrict__ h, const float* __restrict__ W2,
    const float* __restrict__ b2, float* __restrict__ logits)
{
    const int t = blockIdx.x;
    const int tid = threadIdx.x;
    const float* hrow = h + (size_t)t * HD;

    float acc[NE];
#pragma unroll
    for (int e = 0; e < NE; ++e) acc[e] = 0.f;
    for (int f = tid; f < HD; f += 256) {
        float hv = hrow[f];
        float4 w0 = *(const float4*)(W2 + (size_t)f * NE);
        float4 w1 = *(const float4*)(W2 + (size_t)f * NE + 4);
        acc[0] += hv * w0.x; acc[1] += hv * w0.y; acc[2] += hv * w0.z; acc[3] += hv * w0.w;
        acc[4] += hv * w1.x; acc[5] += hv * w1.y; acc[6] += hv * w1.z; acc[7] += hv * w1.w;
    }
    __shared__ float red[256][NE];
#pragma unroll
    for (int e = 0; e < NE; ++e) red[tid][e] = acc[e];
    __syncthreads();
    for (int s = 128; s > 0; s >>= 1) {
        if (tid < s) {
#pragma unroll
            for (int e = 0; e < NE; ++e) red[tid][e] += red[tid + s][e];
        }
        __syncthreads();
    }
    if (tid < NE) logits[(size_t)t * NE + tid] = red[0][tid] + b2[tid];
}

// ---------------- Kernel 5a: zero hflag + count --------------------------
__global__ __launch_bounds__(256) void zero_fix_kernel(
    float* __restrict__ hflag, int* __restrict__ count)
{
    int i = blockIdx.x * 256 + threadIdx.x;
    ((float4*)hflag)[i] = make_float4(0.f, 0.f, 0.f, 0.f);
    if (i == 0) *count = 0;
}

// ---------------- Kernel 5b: flag near-ties, compact list ----------------
__global__ __launch_bounds__(256) void flag_compact_kernel(
    const float* __restrict__ logits, int* __restrict__ count, int* __restrict__ list)
{
    int t = blockIdx.x * 256 + threadIdx.x;
    float l[NE];
    *(float4*)(&l[0]) = *(const float4*)(logits + (size_t)t * NE);
    *(float4*)(&l[4]) = *(const float4*)(logits + (size_t)t * NE + 4);
    float a = -1e30f, b = -1e30f, c = -1e30f;
#pragma unroll
    for (int e = 0; e < NE; ++e) {
        float v = l[e];
        if (v > a) { c = b; b = a; a = v; }
        else if (v > b) { c = b; b = v; }
        else if (v > c) { c = v; }
    }
    if (b - c < TAU) {
        int p = atomicAdd(count, 1);
        if (p < MAXFLAG) list[p] = t;
    }
}

// ---------------- Kernel 6a: batched exact pre-activation h for flagged --
__global__ __launch_bounds__(256) void fixup_stageA(
    const float* __restrict__ x, const float* __restrict__ W1,
    const int* __restrict__ count_p, const int* __restrict__ list,
    float* __restrict__ hflag)
{
    __shared__ float xs[GSIZE][256];          // 16 KB
    __shared__ float red[4][GSIZE][64];       // 16 KB
    const int tid = threadIdx.x;
    const int fl  = tid & 63;
    const int kg  = tid >> 6;
    const int f   = blockIdx.x * 64 + fl;
    const int kbase = blockIdx.y * 1024;
    int count = *count_p;
    if (count > MAXFLAG) count = MAXFLAG;

    for (int g = 0; g * GSIZE < count; ++g) {
        const int gbase = g * GSIZE;
        int ntok = count - gbase; if (ntok > GSIZE) ntok = GSIZE;

        float acc[GSIZE];
#pragma unroll
        for (int t = 0; t < GSIZE; ++t) acc[t] = 0.f;

        for (int kb = 0; kb < 1024; kb += 256) {
            __syncthreads();
            for (int i = tid; i < ntok * 256; i += 256) {
                int t = i >> 8, kk = i & 255;
                xs[t][kk] = x[(size_t)list[gbase + t] * HD + kbase + kb + kk];
            }
            __syncthreads();
            for (int j = 0; j < 64; ++j) {
                int kk = kg * 64 + j;
                float w = W1[(size_t)(kbase + kb + kk) * HD + f];
#pragma unroll
                for (int t = 0; t < GSIZE; ++t) acc[t] += xs[t][kk] * w;
            }
        }
        __syncthreads();
#pragma unroll
        for (int t = 0; t < GSIZE; ++t) red[kg][t][fl] = acc[t];
        __syncthreads();
        if (kg == 0) {
            for (int t = 0; t < ntok; ++t) {
                float v = red[0][t][fl] + red[1][t][fl] + red[2][t][fl] + red[3][t][fl];
                atomicAdd(&hflag[(size_t)(gbase + t) * HD + f], v);
            }
        }
        __syncthreads();
    }
}

// ---------------- Kernel 6b: exact logits for flagged tokens -------------
__global__ __launch_bounds__(256) void fixup_stageB(
    const float* __restrict__ hflag, const float* __restrict__ b1,
    const float* __restrict__ W2, const float* __restrict__ b2,
    const int* __restrict__ count_p, const int* __restrict__ list,
    float* __restrict__ logits)
{
    int count = *count_p;
    if (count > MAXFLAG) count = MAXFLAG;
    const int b = blockIdx.x;
    if (b >= count) return;
    const int tok = list[b];
    const int tid = threadIdx.x;

    float acc[NE];
#pragma unroll
    for (int e = 0; e < NE; ++e) acc[e] = 0.f;
    for (int f = tid; f < HD; f += 256) {
        float hv = hflag[(size_t)b * HD + f] + b1[f];
        hv = hv > 0.f ? hv : 0.f;
        float4 w0 = *(const float4*)(W2 + (size_t)f * NE);
        float4 w1 = *(const float4*)(W2 + (size_t)f * NE + 4);
        acc[0] += hv * w0.x; acc[1] += hv * w0.y; acc[2] += hv * w0.z; acc[3] += hv * w0.w;
        acc[4] += hv * w1.x; acc[5] += hv * w1.y; acc[6] += hv * w1.z; acc[7] += hv * w1.w;
    }
    __shared__ float red[256][NE];
#pragma unroll
    for (int e = 0; e < NE; ++e) red[tid][e] = acc[e];
    __syncthreads();
    for (int s = 128; s > 0; s >>= 1) {
        if (tid < s) {
#pragma unroll
            for (int e = 0; e < NE; ++e) red[tid][e] += red[tid + s][e];
        }
        __syncthreads();
    }
    if (tid < NE) logits[(size_t)tok * NE + tid] = red[0][tid] + b2[tid];
}

// ---------------- Kernel 7: softmax + top2 + renorm + partial sums -------
__global__ __launch_bounds__(256) void softmax_top2_kernel(
    const float* __restrict__ logits, float* __restrict__ probs_out,
    float* __restrict__ top2prob, int* __restrict__ top2idx,
    float* __restrict__ partial)
{
    const int tid = threadIdx.x;
    const int t = blockIdx.x * 256 + tid;

    float l[NE];
    *(float4*)(&l[0]) = *(const float4*)(logits + (size_t)t * NE);
    *(float4*)(&l[4]) = *(const float4*)(logits + (size_t)t * NE + 4);

    float mx = l[0];
#pragma unroll
    for (int e = 1; e < NE; ++e) mx = fmaxf(mx, l[e]);
    float p[NE], sum = 0.f;
#pragma unroll
    for (int e = 0; e < NE; ++e) { p[e] = __expf(l[e] - mx); sum += p[e]; }
    float inv = 1.f / sum;
#pragma unroll
    for (int e = 0; e < NE; ++e) p[e] *= inv;

#pragma unroll
    for (int e = 0; e < NE; ++e) probs_out[(size_t)t * NE + e] = p[e];

    float b1v = -1e30f, b2v = -1e30f;
    int i1 = 0, i2 = 0;
#pragma unroll
    for (int e = 0; e < NE; ++e) {
        float v = l[e];
        if (v > b1v) { b2v = b1v; i2 = i1; b1v = v; i1 = e; }
        else if (v > b2v) { b2v = v; i2 = e; }
    }
    float p1 = 0.f, p2 = 0.f;
#pragma unroll
    for (int e = 0; e < NE; ++e) { if (e == i1) p1 = p[e]; if (e == i2) p2 = p[e]; }
    float s = p1 + p2 + 1e-8f;
    top2prob[2 * t]     = p1 / s;
    top2prob[2 * t + 1] = p2 / s;
    top2idx[2 * t]      = i1;
    top2idx[2 * t + 1]  = i2;

    __shared__ float red[256][NE];
#pragma unroll
    for (int e = 0; e < NE; ++e) red[tid][e] = p[e];
    __syncthreads();
    for (int sdx = 128; sdx > 0; sdx >>= 1) {
        if (tid < sdx) {
#pragma unroll
            for (int e = 0; e < NE; ++e) red[tid][e] += red[tid + sdx][e];
        }
        __syncthreads();
    }
    if (tid < NE) partial[blockIdx.x * NE + tid] = red[0][tid];
}

// ---------------- Kernel 8: sequential capacity scan + slot map + aux ----
__global__ __launch_bounds__(256) void scan_dispatch_kernel(
    const int* __restrict__ top2idx, const float* __restrict__ top2prob,
    const float* __restrict__ partial, int* __restrict__ slot_pos,
    float* __restrict__ slot_val, float* __restrict__ aux_out)
{
    const int tid = threadIdx.x;
    const int ITEMS = NSEL / 256;

    for (int i = tid; i < NTOK * NE; i += 256) { slot_pos[i] = -1; slot_val[i] = 0.f; }

    int cnt[NE];
#pragma unroll
    for (int e = 0; e < NE; ++e) cnt[e] = 0;
    const int base = tid * ITEMS;
    for (int j = 0; j < ITEMS; ++j) {
        int v = top2idx[base + j];
#pragma unroll
        for (int e = 0; e < NE; ++e) cnt[e] += (v == e);
    }

    __shared__ int scnt[256][NE];
    __shared__ int tot[NE];
#pragma unroll
    for (int e = 0; e < NE; ++e) scnt[tid][e] = cnt[e];
    __syncthreads();

    if (tid < NE) {
        int run = 0;
        for (int i = 0; i < 256; ++i) {
            int c = scnt[i][tid];
            scnt[i][tid] = run;
            run += c;
        }
        tot[tid] = run;
    }
    __syncthreads();

    int off[NE];
#pragma unroll
    for (int e = 0; e < NE; ++e) off[e] = scnt[tid][e];
    for (int j = 0; j < ITEMS; ++j) {
        int item = base + j;
        int v = top2idx[item];
        int pos = 0;
#pragma unroll
        for (int e = 0; e < NE; ++e) { if (v == e) { pos = off[e]; off[e]++; } }
        if (pos < CAP) {
            int tok = item >> 1;
            slot_pos[tok * NE + v] = pos;
            slot_val[tok * NE + v] = top2prob[item];
        }
    }

    if (tid == 0) {
        float aux = 0.f;
#pragma unroll
        for (int e = 0; e < NE; ++e) {
            float pp = 0.f;
            for (int b = 0; b < 16; ++b) pp += partial[b * NE + e];
            aux += (pp / (float)NTOK) * ((float)tot[e] / (float)NSEL);
        }
        aux_out[0] = aux * (float)NE;
    }
}

// ---------------- Kernel 9: fused zero-fill + scatter --------------------
__global__ __launch_bounds__(256) void fill_outputs_kernel(
    const int* __restrict__ slot_pos, const float* __restrict__ slot_val,
    float* __restrict__ out)
{
    const int TOTALQ = 25165824;   // 2*NTOK*NE*CAP / 4
    const int HALFQ  = 12582912;
    const int ROWQ   = CAP / 4;
    int stride = gridDim.x * blockDim.x;
    for (int q = blockIdx.x * blockDim.x + threadIdx.x; q < TOTALQ; q += stride) {
        bool isdisp = q < HALFQ;
        int local = isdisp ? q : q - HALFQ;
        int tokE = local / ROWQ;
        int p = (local - tokE * ROWQ) * 4;
        int sp = slot_pos[tokE];
        float4 v = make_float4(0.f, 0.f, 0.f, 0.f);
        if (sp >= p && sp < p + 4) {
            float val = isdisp ? 1.0f : slot_val[tokE];
            ((float*)&v)[sp - p] = val;
        }
        *(float4*)(out + (size_t)q * 4) = v;
    }
}

// ---------------- host ---------------------------------------------------
extern "C" void kernel_launch(void* const* d_in, const int* in_sizes, int n_in,
                              void* d_out, int out_size, void* d_ws, size_t ws_size,
                              hipStream_t stream)
{
    const float* x  = (const float*)d_in[0];
    const float* W1 = (const float*)d_in[1];
    const float* b1 = (const float*)d_in[2];
    const float* W2 = (const float*)d_in[3];
    const float* b2 = (const float*)d_in[4];
    float* out = (float*)d_out;

    // Staging in d_out (overwritten by fill_outputs at the end):
    ushort_t* xhi   = (ushort_t*)(out);                 // panel format
    ushort_t* xlo   = (ushort_t*)(out + 8388608);
    ushort_t* w1thi = (ushort_t*)(out + 16777216);
    ushort_t* w1tlo = (ushort_t*)(out + 25165824);
    float*    hflag = out + HFLAG_OFF;                  // MAXFLAG*HD floats (1 MB)
    float* hbuf = out + COMB_OFF;                       // h (fp32, 67 MB)

    // ws layout (float offsets)
    float* ws       = (float*)d_ws;
    float* logits   = ws;
    float* top2prob = ws + 32768;
    int*   top2idx  = (int*)(ws + 40960);
    float* partial  = ws + 49152;
    int*   slot_pos = (int*)(ws + 49280);
    float* slot_val = ws + 82048;
    int*   count    = (int*)(ws + 114816);
    int*   list     = (int*)(ws + 114817);

    convert_x_panel<<<dim3(128, 32), 256, 0, stream>>>(x, xhi, xlo);
    convert_w1_panel<<<dim3(128, 32), 256, 0, stream>>>(W1, w1thi, w1tlo);
    gemm32_kernel<<<dim3(32, 16), 256, 0, stream>>>(xhi, xlo, w1thi, w1tlo, b1, hbuf);
    logits_kernel<<<NTOK, 256, 0, stream>>>(hbuf, W2, b2, logits);
    zero_fix_kernel<<<256, 256, 0, stream>>>(hflag, count);
    flag_compact_kernel<<<16, 256, 0, stream>>>(logits, count, list);
    fixup_stageA<<<dim3(64, 4), 256, 0, stream>>>(x, W1, count, list, hflag);
    fixup_stageB<<<MAXFLAG, 256, 0, stream>>>(hflag, b1, W2, b2, count, list, logits);
    softmax_top2_kernel<<<16, 256, 0, stream>>>(logits, out + PROBS_OFF, top2prob, top2idx, partial);
    scan_dispatch_kernel<<<1, 256, 0, stream>>>(top2idx, top2prob, partial, slot_pos, slot_val, out + AUX_OFF);
    fill_outputs_kernel<<<4096, 256, 0, stream>>>(slot_pos, slot_val, out);
}

// Round 9
// 839.721 us; speedup vs baseline: 2.6127x; 1.2068x over previous
//
#include <hip/hip_runtime.h>
#include <cmath>

// Problem constants (fixed by reference setup)
#define NTOK 4096            // B*S = 2*2048
#define HD   4096            // hidden dim
#define NE   8               // experts
#define CAP  1536            // int(B*S*1.5*2/8)
#define NSEL 8192            // NTOK * TOP_K
#define TAU  2.5e-3f         // near-tie gap threshold (fp16 gemm: sigma~4.4e-4 -> 5.7 sigma)
#define MAXFLAG 256
#define GSIZE 32             // flagged tokens per W1 pass in stageA

// d_out layout (float element offsets)
#define COMB_OFF  50331648UL   // NTOK*NE*CAP
#define PROBS_OFF 100663296UL  // 2*NTOK*NE*CAP
#define AUX_OFF   100696064UL  // PROBS_OFF + NTOK*NE
#define HFLAG_OFF 25165824UL   // hflag scratch inside dispatch region (4 MB)

typedef unsigned short ushort_t;
typedef _Float16 half_t;
typedef half_t half8 __attribute__((ext_vector_type(8)));
typedef float floatx16 __attribute__((ext_vector_type(16)));

// Panel format: [group g (32 rows)][kstep ks (32 k)][2048 bytes]; 16B chunk u:
// h=u>>6, l=u&63, r=l&31, oh=l>>5 -> (row r, k=h*16+oh*8+j). Staging: lane l
// sources chunk l / 64+l -> each global_load_lds = one contiguous 1KB burst.

// ---- async 16B global->LDS (gsrc per-lane; lds dest = base+lane*16) ------
__device__ __forceinline__ void async_copy16(const void* g, void* l) {
    __builtin_amdgcn_global_load_lds(
        (const __attribute__((address_space(1))) unsigned int*)g,
        (__attribute__((address_space(3))) unsigned int*)l, 16, 0, 0);
}

// ---------------- Kernel 1: x -> fp16 panels ------------------------------
// grid (128 g, 32 q); block covers rows g*32..+32, k = q*128..+128.
__global__ __launch_bounds__(256) void convert_x_panel(
    const float* __restrict__ x, ushort_t* __restrict__ xp)
{
    __shared__ float xs[32 * 128];      // 16 KB
    const int g = blockIdx.x, q = blockIdx.y, t = threadIdx.x;
#pragma unroll
    for (int i = 0; i < 4; ++i) {
        int idx = i * 256 + t;
        int row = idx >> 5, c4 = (idx & 31) * 4;
        float4 v = *(const float4*)(x + (size_t)(g * 32 + row) * HD + q * 128 + c4);
        *(float4*)(&xs[row * 128 + c4]) = v;
    }
    __syncthreads();
#pragma unroll
    for (int it = 0; it < 2; ++it) {
        int c = it * 256 + t;
        int s = c >> 7, u = c & 127;
        int h = u >> 6, l = u & 63, r = l & 31, oh = l >> 5;
        int kl = s * 32 + h * 16 + oh * 8;
        half8 h8;
#pragma unroll
        for (int j = 0; j < 8; ++j) h8[j] = (half_t)xs[r * 128 + kl + j];
        size_t off = ((size_t)(g * 128 + q * 4 + s)) * 1024 + u * 8;
        *(half8*)(xp + off) = h8;
    }
}

// ---------------- Kernel 2: W1 -> W1^T fp16 panels (transpose) ------------
__global__ __launch_bounds__(256) void convert_w1_panel(
    const float* __restrict__ W1, ushort_t* __restrict__ wp)
{
    __shared__ float ws[32 * 129];      // padded transpose stage
    const int gn = blockIdx.x, q = blockIdx.y, t = threadIdx.x;
#pragma unroll
    for (int i = 0; i < 4; ++i) {
        int idx = i * 256 + t;
        int kr = idx >> 3, c4 = (idx & 7) * 4;
        float4 v = *(const float4*)(W1 + (size_t)(q * 128 + kr) * HD + gn * 32 + c4);
        ws[(c4 + 0) * 129 + kr] = v.x;
        ws[(c4 + 1) * 129 + kr] = v.y;
        ws[(c4 + 2) * 129 + kr] = v.z;
        ws[(c4 + 3) * 129 + kr] = v.w;
    }
    __syncthreads();
#pragma unroll
    for (int it = 0; it < 2; ++it) {
        int c = it * 256 + t;
        int s = c >> 7, u = c & 127;
        int h = u >> 6, l = u & 63, r = l & 31, oh = l >> 5;
        int kl = s * 32 + h * 16 + oh * 8;
        half8 h8;
#pragma unroll
        for (int j = 0; j < 8; ++j) h8[j] = (half_t)ws[r * 129 + kl + j];
        size_t off = ((size_t)(gn * 128 + q * 4 + s)) * 1024 + u * 8;
        *(half8*)(wp + off) = h8;
    }
}

// ---------------- Kernel 3: h = relu(x@W1 + b1), single-term fp16 ---------
// Block 256x128, 4 waves (2x2), wave tile 128x64 = 4x2 of 32x32. BK=64 via
// two 24KB sub-buffers (48 KB total, 2 blocks/CU). Per sub-buffer (ushort
// offs): A 0 (8 grp x 1024), B 8192 (4 grp x 1024).
__global__ __launch_bounds__(256, 2) void gemm16_kernel(
    const ushort_t* __restrict__ Ap, const ushort_t* __restrict__ Bp,
    const float* __restrict__ bias,
    float* __restrict__ C)
{
    __shared__ __attribute__((aligned(16))) ushort_t lds[24576];  // 48 KB

    const int tid  = threadIdx.x;
    const int wave = tid >> 6;
    const int lane = tid & 63;
    const int l31  = lane & 31;
    const int lh   = lane >> 5;
    const int m0 = blockIdx.y * 256;
    const int n0 = blockIdx.x * 128;
    const int wm = wave >> 1;
    const int wn = wave & 1;

    floatx16 acc[4][2];
#pragma unroll
    for (int mi = 0; mi < 4; ++mi)
#pragma unroll
        for (int ni = 0; ni < 2; ++ni)
#pragma unroll
            for (int r = 0; r < 16; ++r) acc[mi][ni][r] = 0.f;

    const int lsrc = lane * 8;         // 16 B per lane
    const ushort_t* srcA = Ap + (size_t)(blockIdx.y * 8 + 2 * wave) * 128 * 1024 + lsrc;
    const ushort_t* srcB = Bp + (size_t)(blockIdx.x * 4 + wave) * 128 * 1024 + lsrc;

    for (int ks = 0; ks < 128; ks += 2) {
#pragma unroll
        for (int s = 0; s < 2; ++s) {
            ushort_t* buf = lds + s * 12288;
            const size_t po = (size_t)(ks + s) * 1024;
            async_copy16(srcA + po,                    buf + 2 * wave * 1024);
            async_copy16(srcA + po + 512,              buf + 2 * wave * 1024 + 512);
            async_copy16(srcA + 128 * 1024 + po,       buf + (2 * wave + 1) * 1024);
            async_copy16(srcA + 128 * 1024 + po + 512, buf + (2 * wave + 1) * 1024 + 512);
            async_copy16(srcB + po,       buf + 8192 + wave * 1024);
            async_copy16(srcB + po + 512, buf + 8192 + wave * 1024 + 512);
        }
        __syncthreads();

#pragma unroll
        for (int s = 0; s < 2; ++s) {
            const ushort_t* buf = lds + s * 12288;
#pragma unroll
            for (int h = 0; h < 2; ++h) {
                half8 ah[4], bh[2];
#pragma unroll
                for (int mi = 0; mi < 4; ++mi)
                    ah[mi] = *(const half8*)&buf[(wm * 4 + mi) * 1024 + h * 512 + lane * 8];
#pragma unroll
                for (int ni = 0; ni < 2; ++ni)
                    bh[ni] = *(const half8*)&buf[8192 + (wn * 2 + ni) * 1024 + h * 512 + lane * 8];
#pragma unroll
                for (int mi = 0; mi < 4; ++mi)
#pragma unroll
                    for (int ni = 0; ni < 2; ++ni)
                        acc[mi][ni] = __builtin_amdgcn_mfma_f32_32x32x16_f16(ah[mi], bh[ni], acc[mi][ni], 0, 0, 0);
            }
        }
        __syncthreads();
    }

    // Epilogue: bias + relu. C/D map: col = l31, row = (r&3)+8*(r>>2)+4*lh
    const int nc0 = n0 + wn * 64 + l31;
    float b1v0 = bias[nc0], b1v1 = bias[nc0 + 32];
#pragma unroll
    for (int mi = 0; mi < 4; ++mi) {
#pragma unroll
        for (int r = 0; r < 16; ++r) {
            int row = m0 + wm * 128 + mi * 32 + (r & 3) + 8 * (r >> 2) + 4 * lh;
            float* crow = C + (size_t)row * HD + nc0;
            float v0 = acc[mi][0][r] + b1v0;
            float v1 = acc[mi][1][r] + b1v1;
            crow[0]  = v0 > 0.f ? v0 : 0.f;
            crow[32] = v1 > 0.f ? v1 : 0.f;
        }
    }
}

// ---------------- Kernel 4: logits = h @ W2 + b2 (fp32) ------------------
__global__ __launch_bounds__(256) void logits_kernel(
    const float* __restrict__ h, const float* __restrict__ W2,
    const float* __restrict__ b2, float* __restrict__ logits)
{
    const int t = blockIdx.x;
    const int tid = threadIdx.x;
    const float* hrow = h + (size_t)t * HD;

    float acc[NE];
#pragma unroll
    for (int e = 0; e < NE; ++e) acc[e] = 0.f;
    for (int f = tid; f < HD; f += 256) {
        float hv = hrow[f];
        float4 w0 = *(const float4*)(W2 + (size_t)f * NE);
        float4 w1 = *(const float4*)(W2 + (size_t)f * NE + 4);
        acc[0] += hv * w0.x; acc[1] += hv * w0.y; acc[2] += hv * w0.z; acc[3] += hv * w0.w;
        acc[4] += hv * w1.x; acc[5] += hv * w1.y; acc[6] += hv * w1.z; acc[7] += hv * w1.w;
    }
    __shared__ float red[256][NE];
#pragma unroll
    for (int e = 0; e < NE; ++e) red[tid][e] = acc[e];
    __syncthreads();
    for (int s = 128; s > 0; s >>= 1) {
        if (tid < s) {
#pragma unroll
            for (int e = 0; e < NE; ++e) red[tid][e] += red[tid + s][e];
        }
        __syncthreads();
    }
    if (tid < NE) logits[(size_t)t * NE + tid] = red[0][tid] + b2[tid];
}

// ---------------- Kernel 5: zero dispatch+combine (403 MB streaming) -----
__global__ __launch_bounds__(256) void zero_out_kernel(float* __restrict__ out)
{
    const int TOTALQ = 25165824;   // 2*NTOK*NE*CAP / 4
    int stride = gridDim.x * 256;
    float4 z = make_float4(0.f, 0.f, 0.f, 0.f);
    for (int q = blockIdx.x * 256 + threadIdx.x; q < TOTALQ; q += stride)
        ((float4*)out)[q] = z;
}

// ---------------- Kernel 5b: init count ----------------------------------
__global__ void init_count_kernel(int* __restrict__ count) { *count = 0; }

// ---------------- Kernel 5c: re-zero hflag residue (inside dispatch out) --
__global__ __launch_bounds__(256) void zero_hflag_kernel(float* __restrict__ hflag)
{
    int i = blockIdx.x * 256 + threadIdx.x;   // 1024 blocks: 262144 float4 = 4 MB
    ((float4*)hflag)[i] = make_float4(0.f, 0.f, 0.f, 0.f);
}

// ---------------- Kernel 6: flag near-ties, compact list -----------------
__global__ __launch_bounds__(256) void flag_compact_kernel(
    const float* __restrict__ logits, int* __restrict__ count, int* __restrict__ list)
{
    int t = blockIdx.x * 256 + threadIdx.x;
    float l[NE];
    *(float4*)(&l[0]) = *(const float4*)(logits + (size_t)t * NE);
    *(float4*)(&l[4]) = *(const float4*)(logits + (size_t)t * NE + 4);
    float a = -1e30f, b = -1e30f, c = -1e30f;
#pragma unroll
    for (int e = 0; e < NE; ++e) {
        float v = l[e];
        if (v > a) { c = b; b = a; a = v; }
        else if (v > b) { c = b; b = v; }
        else if (v > c) { c = v; }
    }
    if (b - c < TAU) {
        int p = atomicAdd(count, 1);
        if (p < MAXFLAG) list[p] = t;
    }
}

// ---------------- Kernel 7a: batched exact pre-activation h for flagged --
// grid (64 f-chunks, 4 k-splits); one W1 pass per 32 flagged tokens.
__global__ __launch_bounds__(256) void fixup_stageA(
    const float* __restrict__ x, const float* __restrict__ W1,
    const int* __restrict__ count_p, const int* __restrict__ list,
    float* __restrict__ hflag)
{
    __shared__ float xs[GSIZE][256];          // 32 KB
    __shared__ float red[4][GSIZE][64];       // 32 KB
    const int tid = threadIdx.x;
    const int fl  = tid & 63;
    const int kg  = tid >> 6;
    const int f   = blockIdx.x * 64 + fl;
    const int kbase = blockIdx.y * 1024;
    int count = *count_p;
    if (count > MAXFLAG) count = MAXFLAG;

    for (int g = 0; g * GSIZE < count; ++g) {
        const int gbase = g * GSIZE;
        int ntok = count - gbase; if (ntok > GSIZE) ntok = GSIZE;

        float acc[GSIZE];
#pragma unroll
        for (int t = 0; t < GSIZE; ++t) acc[t] = 0.f;

        for (int kb = 0; kb < 1024; kb += 256) {
            __syncthreads();
            for (int i = tid; i < ntok * 256; i += 256) {
                int t = i >> 8, kk = i & 255;
                xs[t][kk] = x[(size_t)list[gbase + t] * HD + kbase + kb + kk];
            }
            __syncthreads();
            for (int j = 0; j < 64; ++j) {
                int kk = kg * 64 + j;
                float w = W1[(size_t)(kbase + kb + kk) * HD + f];
#pragma unroll
                for (int t = 0; t < GSIZE; ++t) acc[t] += xs[t][kk] * w;
            }
        }
        __syncthreads();
#pragma unroll
        for (int t = 0; t < GSIZE; ++t) red[kg][t][fl] = acc[t];
        __syncthreads();
        if (kg == 0) {
            for (int t = 0; t < ntok; ++t) {
                float v = red[0][t][fl] + red[1][t][fl] + red[2][t][fl] + red[3][t][fl];
                atomicAdd(&hflag[(size_t)(gbase + t) * HD + f], v);
            }
        }
        __syncthreads();
    }
}

// ---------------- Kernel 7b: exact logits for flagged tokens -------------
__global__ __launch_bounds__(256) void fixup_stageB(
    const float* __restrict__ hflag, const float* __restrict__ b1,
    const float* __restrict__ W2, const float* __restrict__ b2,
    const int* __restrict__ count_p, const int* __restrict__ list,
    float* __restrict__ logits)
{
    int count = *count_p;
    if (count > MAXFLAG) count = MAXFLAG;
    const int b = blockIdx.x;
    if (b >= count) return;
    const int tok = list[b];
    const int tid = threadIdx.x;

    float acc[NE];
#pragma unroll
    for (int e = 0; e < NE; ++e) acc[e] = 0.f;
    for (int f = tid; f < HD; f += 256) {
        float hv = hflag[(size_t)b * HD + f] + b1[f];
        hv = hv > 0.f ? hv : 0.f;
        float4 w0 = *(const float4*)(W2 + (size_t)f * NE);
        float4 w1 = *(const float4*)(W2 + (size_t)f * NE + 4);
        acc[0] += hv * w0.x; acc[1] += hv * w0.y; acc[2] += hv * w0.z; acc[3] += hv * w0.w;
        acc[4] += hv * w1.x; acc[5] += hv * w1.y; acc[6] += hv * w1.z; acc[7] += hv * w1.w;
    }
    __shared__ float red[256][NE];
#pragma unroll
    for (int e = 0; e < NE; ++e) red[tid][e] = acc[e];
    __syncthreads();
    for (int s = 128; s > 0; s >>= 1) {
        if (tid < s) {
#pragma unroll
            for (int e = 0; e < NE; ++e) red[tid][e] += red[tid + s][e];
        }
        __syncthreads();
    }
    if (tid < NE) logits[(size_t)tok * NE + tid] = red[0][tid] + b2[tid];
}

// ---------------- Kernel 8: softmax + top2 + renorm + partial sums -------
__global__ __launch_bounds__(256) void softmax_top2_kernel(
    const float* __restrict__ logits, float* __restrict__ probs_out,
    float* __restrict__ top2prob, int* __restrict__ top2idx,
    float* __restrict__ partial)
{
    const int tid = threadIdx.x;
    const int t = blockIdx.x * 256 + tid;

    float l[NE];
    *(float4*)(&l[0]) = *(const float4*)(logits + (size_t)t * NE);
    *(float4*)(&l[4]) = *(const float4*)(logits + (size_t)t * NE + 4);

    float mx = l[0];
#pragma unroll
    for (int e = 1; e < NE; ++e) mx = fmaxf(mx, l[e]);
    float p[NE], sum = 0.f;
#pragma unroll
    for (int e = 0; e < NE; ++e) { p[e] = __expf(l[e] - mx); sum += p[e]; }
    float inv = 1.f / sum;
#pragma unroll
    for (int e = 0; e < NE; ++e) p[e] *= inv;

#pragma unroll
    for (int e = 0; e < NE; ++e) probs_out[(size_t)t * NE + e] = p[e];

    float b1v = -1e30f, b2v = -1e30f;
    int i1 = 0, i2 = 0;
#pragma unroll
    for (int e = 0; e < NE; ++e) {
        float v = l[e];
        if (v > b1v) { b2v = b1v; i2 = i1; b1v = v; i1 = e; }
        else if (v > b2v) { b2v = v; i2 = e; }
    }
    float p1 = 0.f, p2 = 0.f;
#pragma unroll
    for (int e = 0; e < NE; ++e) { if (e == i1) p1 = p[e]; if (e == i2) p2 = p[e]; }
    float s = p1 + p2 + 1e-8f;
    top2prob[2 * t]     = p1 / s;
    top2prob[2 * t + 1] = p2 / s;
    top2idx[2 * t]      = i1;
    top2idx[2 * t + 1]  = i2;

    __shared__ float red[256][NE];
#pragma unroll
    for (int e = 0; e < NE; ++e) red[tid][e] = p[e];
    __syncthreads();
    for (int sdx = 128; sdx > 0; sdx >>= 1) {
        if (tid < sdx) {
#pragma unroll
            for (int e = 0; e < NE; ++e) red[tid][e] += red[tid + sdx][e];
        }
        __syncthreads();
    }
    if (tid < NE) partial[blockIdx.x * NE + tid] = red[0][tid];
}

// ---------------- Kernel 9: sequential capacity scan + slot map + aux ----
__global__ __launch_bounds__(256) void scan_dispatch_kernel(
    const int* __restrict__ top2idx, const float* __restrict__ top2prob,
    const float* __restrict__ partial, int* __restrict__ slot_pos,
    float* __restrict__ slot_val, float* __restrict__ aux_out)
{
    const int tid = threadIdx.x;
    const int ITEMS = NSEL / 256;

    for (int i = tid; i < NTOK * NE; i += 256) { slot_pos[i] = -1; slot_val[i] = 0.f; }

    int cnt[NE];
#pragma unroll
    for (int e = 0; e < NE; ++e) cnt[e] = 0;
    const int base = tid * ITEMS;
    for (int j = 0; j < ITEMS; ++j) {
        int v = top2idx[base + j];
#pragma unroll
        for (int e = 0; e < NE; ++e) cnt[e] += (v == e);
    }

    __shared__ int scnt[256][NE];
    __shared__ int tot[NE];
#pragma unroll
    for (int e = 0; e < NE; ++e) scnt[tid][e] = cnt[e];
    __syncthreads();

    if (tid < NE) {
        int run = 0;
        for (int i = 0; i < 256; ++i) {
            int c = scnt[i][tid];
            scnt[i][tid] = run;
            run += c;
        }
        tot[tid] = run;
    }
    __syncthreads();

    int off[NE];
#pragma unroll
    for (int e = 0; e < NE; ++e) off[e] = scnt[tid][e];
    for (int j = 0; j < ITEMS; ++j) {
        int item = base + j;
        int v = top2idx[item];
        int pos = 0;
#pragma unroll
        for (int e = 0; e < NE; ++e) { if (v == e) { pos = off[e]; off[e]++; } }
        if (pos < CAP) {
            int tok = item >> 1;
            slot_pos[tok * NE + v] = pos;
            slot_val[tok * NE + v] = top2prob[item];
        }
    }

    if (tid == 0) {
        float aux = 0.f;
#pragma unroll
        for (int e = 0; e < NE; ++e) {
            float pp = 0.f;
            for (int b = 0; b < 16; ++b) pp += partial[b * NE + e];
            aux += (pp / (float)NTOK) * ((float)tot[e] / (float)NSEL);
        }
        aux_out[0] = aux * (float)NE;
    }
}

// ---------------- Kernel 10: sparse scatter into zeroed outputs ----------
__global__ __launch_bounds__(256) void scatter_kernel(
    const int* __restrict__ slot_pos, const float* __restrict__ slot_val,
    float* __restrict__ out)
{
    int i = blockIdx.x * 256 + threadIdx.x;   // tok*NE + e, 0..32767
    int sp = slot_pos[i];
    if (sp >= 0) {
        out[(size_t)i * CAP + sp] = 1.0f;
        out[COMB_OFF + (size_t)i * CAP + sp] = slot_val[i];
    }
}

// ---------------- host ---------------------------------------------------
extern "C" void kernel_launch(void* const* d_in, const int* in_sizes, int n_in,
                              void* d_out, int out_size, void* d_ws, size_t ws_size,
                              hipStream_t stream)
{
    const float* x  = (const float*)d_in[0];
    const float* W1 = (const float*)d_in[1];
    const float* b1 = (const float*)d_in[2];
    const float* W2 = (const float*)d_in[3];
    const float* b2 = (const float*)d_in[4];
    float* out = (float*)d_out;

    // Staging in d_out (zeroed by zero_out after consumption; hflag region
    // re-zeroed after fixup since it lives inside the graded dispatch output):
    ushort_t* xp  = (ushort_t*)(out);                   // fp16 panel, 33.5 MB
    ushort_t* wp  = (ushort_t*)(out + 8388608);         // fp16 panel, 33.5 MB
    float*    hflag = out + HFLAG_OFF;                  // MAXFLAG*HD (4 MB)
    float* hbuf = out + COMB_OFF;                       // h fp32, 67 MB

    // ws layout (float offsets)
    float* ws       = (float*)d_ws;
    float* logits   = ws;
    float* top2prob = ws + 32768;
    int*   top2idx  = (int*)(ws + 40960);
    float* partial  = ws + 49152;
    int*   slot_pos = (int*)(ws + 49280);
    float* slot_val = ws + 82048;
    int*   count    = (int*)(ws + 114816);
    int*   list     = (int*)(ws + 114817);

    convert_x_panel<<<dim3(128, 32), 256, 0, stream>>>(x, xp);
    convert_w1_panel<<<dim3(128, 32), 256, 0, stream>>>(W1, wp);
    gemm16_kernel<<<dim3(32, 16), 256, 0, stream>>>(xp, wp, b1, hbuf);
    logits_kernel<<<NTOK, 256, 0, stream>>>(hbuf, W2, b2, logits);
    // panels + hbuf consumed: zero the whole dispatch+combine region now
    // (also zero-inits hflag for stageA's atomicAdd)
    zero_out_kernel<<<8192, 256, 0, stream>>>(out);
    init_count_kernel<<<1, 1, 0, stream>>>(count);
    flag_compact_kernel<<<16, 256, 0, stream>>>(logits, count, list);
    fixup_stageA<<<dim3(64, 4), 256, 0, stream>>>(x, W1, count, list, hflag);
    fixup_stageB<<<MAXFLAG, 256, 0, stream>>>(hflag, b1, W2, b2, count, list, logits);
    // hflag consumed: erase its residue from the dispatch output BEFORE scatter
    zero_hflag_kernel<<<1024, 256, 0, stream>>>(hflag);
    softmax_top2_kernel<<<16, 256, 0, stream>>>(logits, out + PROBS_OFF, top2prob, top2idx, partial);
    scan_dispatch_kernel<<<1, 256, 0, stream>>>(top2idx, top2prob, partial, slot_pos, slot_val, out + AUX_OFF);
    scatter_kernel<<<128, 256, 0, stream>>>(slot_pos, slot_val, out);
}